// Round 1
// baseline (220.719 us; speedup 1.0000x reference)
//
#include <hip/hip_runtime.h>

typedef unsigned short u16;
typedef __attribute__((ext_vector_type(4))) float  f32x4;
typedef __attribute__((ext_vector_type(8))) short  s16x8;

__device__ __forceinline__ u16 f2bf(float f) {
  unsigned u = __builtin_bit_cast(unsigned, f);
  u += 0x7FFFu + ((u >> 16) & 1u);
  return (u16)(u >> 16);
}

__device__ __forceinline__ void gload16(const void* g, void* l) {
  __builtin_amdgcn_global_load_lds(
      (const __attribute__((address_space(1))) void*)g,
      (__attribute__((address_space(3))) void*)l, 16, 0, 0);
}

// ---------------- LayerNorm (fp32 in -> bf16 out) ----------------
__global__ __launch_bounds__(256) void ln_kernel(
    const float* __restrict__ x, const float* __restrict__ gamma,
    const float* __restrict__ beta, u16* __restrict__ xn)
{
  const int row = blockIdx.x, tid = threadIdx.x;
  const float* xr = x + (size_t)row * 1024;
  float4 v = *(const float4*)(xr + tid * 4);
  float s  = v.x + v.y + v.z + v.w;
  float s2 = v.x*v.x + v.y*v.y + v.z*v.z + v.w*v.w;
#pragma unroll
  for (int off = 32; off >= 1; off >>= 1) {
    s  += __shfl_xor(s,  off);
    s2 += __shfl_xor(s2, off);
  }
  __shared__ float red[8];
  const int w = tid >> 6, l = tid & 63;
  if (l == 0) { red[w] = s; red[w + 4] = s2; }
  __syncthreads();
  s  = red[0] + red[1] + red[2] + red[3];
  s2 = red[4] + red[5] + red[6] + red[7];
  const float mu  = s * (1.0f / 1024.0f);
  const float var = s2 * (1.0f / 1024.0f) - mu * mu;
  const float rs  = rsqrtf(var + 1e-5f);
  float4 g  = *(const float4*)(gamma + tid * 4);
  float4 be = *(const float4*)(beta  + tid * 4);
  ushort4 o;
  o.x = f2bf((v.x - mu) * rs * g.x + be.x);
  o.y = f2bf((v.y - mu) * rs * g.y + be.y);
  o.z = f2bf((v.z - mu) * rs * g.z + be.z);
  o.w = f2bf((v.w - mu) * rs * g.w + be.w);
  *(ushort4*)(xn + (size_t)row * 1024 + tid * 4) = o;
}

// ---------------- transpose + fp32->bf16 convert: out[C][R] = in[R][C] ----------------
__global__ void transpose_cvt(const float* __restrict__ in, u16* __restrict__ out,
                              int R, int C)
{
  __shared__ float t[32][33];
  const int bc = blockIdx.x * 32, br = blockIdx.y * 32;
  const int x = threadIdx.x;
#pragma unroll
  for (int i = threadIdx.y; i < 32; i += 8)
    t[i][x] = in[(size_t)(br + i) * C + bc + x];
  __syncthreads();
#pragma unroll
  for (int i = threadIdx.y; i < 32; i += 8)
    out[(size_t)(bc + i) * R + br + x] = f2bf(t[x][i]);
}

// ---------------- GEMM: C[M][N] = A[M][K] * Bt[N][K]^T + bias ----------------
__device__ __forceinline__ void store_out(float* p, float v) { *p = v; }
__device__ __forceinline__ void store_out(u16* p, float v)   { *p = f2bf(v); }

template <typename OutT>
__global__ __launch_bounds__(256) void gemm_bt(
    const u16* __restrict__ A, const u16* __restrict__ Bt,
    const float* __restrict__ bias, OutT* __restrict__ C,
    int M, int N, int K)
{
  __shared__ u16 As[128 * 32];
  __shared__ u16 Bs[128 * 32];
  const int tid = threadIdx.x;
  const int w = tid >> 6, l = tid & 63;
  const int g = l >> 4, li = l & 15;
  const int bm = blockIdx.y * 128, bn = blockIdx.x * 128;
  const int wr = (w >> 1) * 64, wc = (w & 1) * 64;

  f32x4 acc[4][4] = {};

  // staging: 512 16B chunks per tile; thread handles chunks tid and tid+256.
  // chunk c -> row c>>2, slot c&3 ; slot s holds global k-chunk (s ^ (row&3))
  const int ar0 = tid >> 2,          as0 = tid & 3;
  const int ar1 = (tid + 256) >> 2,  as1 = (tid + 256) & 3;
  const u16* pa0 = A  + (size_t)(bm + ar0) * K + 8 * (as0 ^ (ar0 & 3));
  const u16* pa1 = A  + (size_t)(bm + ar1) * K + 8 * (as1 ^ (ar1 & 3));
  const u16* pb0 = Bt + (size_t)(bn + ar0) * K + 8 * (as0 ^ (ar0 & 3));
  const u16* pb1 = Bt + (size_t)(bn + ar1) * K + 8 * (as1 ^ (ar1 & 3));
  u16* la0 = As + w * 512;         // wave-uniform LDS dest (lane writes +l*16B)
  u16* la1 = As + 2048 + w * 512;
  u16* lb0 = Bs + w * 512;
  u16* lb1 = Bs + 2048 + w * 512;

  for (int kt = 0; kt < K; kt += 32) {
    gload16(pa0 + kt, la0);
    gload16(pa1 + kt, la1);
    gload16(pb0 + kt, lb0);
    gload16(pb1 + kt, lb1);
    __syncthreads();

    s16x8 af[4], bf[4];
#pragma unroll
    for (int m = 0; m < 4; ++m) {
      const int row = wr + m * 16 + li;
      af[m] = *(const s16x8*)(As + row * 32 + 8 * (g ^ (row & 3)));
    }
#pragma unroll
    for (int n = 0; n < 4; ++n) {
      const int row = wc + n * 16 + li;
      bf[n] = *(const s16x8*)(Bs + row * 32 + 8 * (g ^ (row & 3)));
    }
#pragma unroll
    for (int m = 0; m < 4; ++m)
#pragma unroll
      for (int n = 0; n < 4; ++n)
        acc[m][n] = __builtin_amdgcn_mfma_f32_16x16x32_bf16(af[m], bf[n], acc[m][n], 0, 0, 0);
    __syncthreads();
  }

#pragma unroll
  for (int n = 0; n < 4; ++n) {
    const int col = bn + wc + n * 16 + li;
    const float bv = bias[col];
#pragma unroll
    for (int m = 0; m < 4; ++m) {
      const int row0 = bm + wr + m * 16 + g * 4;
#pragma unroll
      for (int r = 0; r < 4; ++r)
        store_out(C + (size_t)(row0 + r) * N + col, acc[m][n][r] + bv);
    }
  }
}

// ---------------- flash attention ----------------
// qkv: [4096][3072] bf16, q|k|v each [.,1024] with head h at cols h*64..h*64+63
// out: [4096][1024] bf16 ( [b*2048+n][h*64+d] )
__global__ __launch_bounds__(256) void attn_kernel(
    const u16* __restrict__ qkv, u16* __restrict__ outp)
{
  __shared__ u16 Ks[64 * 64];      // [kv][d], row 128B, chunk-swizzled by (kv&7)
  __shared__ u16 Vt[64 * 64];      // [d][kv], byte-swizzled by ((d^(d>>3))&7)<<4
  __shared__ u16 Pl[4 * 16 * 64];  // per-wave P[q][kv], swizzled by (q>>2)<<5

  const int tid = threadIdx.x;
  const int w = tid >> 6, l = tid & 63;
  const int g = l >> 4, li = l & 15;
  const int qt = blockIdx.x & 31;
  const int h  = (blockIdx.x >> 5) & 15;
  const int bb = blockIdx.x >> 9;
  const size_t baserow = (size_t)bb * 2048;

  // hoisted Q fragments: Q[q=li][d = ks*32 + 8g + j]
  const size_t qrow = baserow + qt * 64 + w * 16 + li;
  const u16* qp = qkv + qrow * 3072 + h * 64 + 8 * g;
  const s16x8 qf0 = *(const s16x8*)(qp);
  const s16x8 qf1 = *(const s16x8*)(qp + 32);

  // staging: 512 chunks; chunk c -> kv c>>3, slot c&7
  const int kr0 = tid >> 3,         ks0 = tid & 7;
  const int kr1 = (tid + 256) >> 3, ks1 = (tid + 256) & 7;
  const u16* kp0 = qkv + (baserow + kr0) * 3072 + 1024 + h * 64 + 8 * (ks0 ^ (kr0 & 7));
  const u16* kp1 = qkv + (baserow + kr1) * 3072 + 1024 + h * 64 + 8 * (ks1 ^ (kr1 & 7));
  const u16* vp0 = qkv + (baserow + kr0) * 3072 + 2048 + h * 64 + 8 * ks0;
  const u16* vp1 = qkv + (baserow + kr1) * 3072 + 2048 + h * 64 + 8 * ks1;
  u16* kl0 = Ks + w * 512;
  u16* kl1 = Ks + 2048 + w * 512;

  float m_run[4], l_run[4];
  f32x4 o[4] = {};
#pragma unroll
  for (int r = 0; r < 4; ++r) { m_run[r] = -1e30f; l_run[r] = 0.0f; }

  char* Pw = (char*)(Pl + w * 1024);

  for (int t = 0; t < 32; ++t) {
    const size_t koff = (size_t)t * 64 * 3072;
    __syncthreads();                       // prev tile's compute done
    gload16(kp0 + koff, kl0);
    gload16(kp1 + koff, kl1);
    const s16x8 v0 = *(const s16x8*)(vp0 + koff);
    const s16x8 v1 = *(const s16x8*)(vp1 + koff);
#pragma unroll
    for (int j = 0; j < 8; ++j) {
      const int d0 = ks0 * 8 + j;
      *(u16*)((char*)Vt + d0 * 128 + ((kr0 * 2) ^ ((((d0 ^ (d0 >> 3)) & 7)) << 4))) = (u16)v0[j];
      const int d1 = ks1 * 8 + j;
      *(u16*)((char*)Vt + d1 * 128 + ((kr1 * 2) ^ ((((d1 ^ (d1 >> 3)) & 7)) << 4))) = (u16)v1[j];
    }
    __syncthreads();                       // staged data visible

    // S = Q K^T   (A=Q 16x32, B=K^T 32x16 read straight from row-major K rows)
    f32x4 s[4] = {};
#pragma unroll
    for (int nk = 0; nk < 4; ++nk) {
      const int kvr = nk * 16 + li;
      const s16x8 kf0 = *(const s16x8*)((char*)Ks + kvr * 128 + 16 * ((0 + g) ^ (kvr & 7)));
      const s16x8 kf1 = *(const s16x8*)((char*)Ks + kvr * 128 + 16 * ((4 + g) ^ (kvr & 7)));
      s[nk] = __builtin_amdgcn_mfma_f32_16x16x32_bf16(qf0, kf0, s[nk], 0, 0, 0);
      s[nk] = __builtin_amdgcn_mfma_f32_16x16x32_bf16(qf1, kf1, s[nk], 0, 0, 0);
    }

    // online softmax; row q = g*4 + r lives in the 16 lanes sharing g
#pragma unroll
    for (int r = 0; r < 4; ++r) {
      float mx = fmaxf(fmaxf(s[0][r], s[1][r]), fmaxf(s[2][r], s[3][r])) * 0.125f;
#pragma unroll
      for (int off = 1; off < 16; off <<= 1) mx = fmaxf(mx, __shfl_xor(mx, off));
      const float mn = fmaxf(m_run[r], mx);
      const float alpha = __expf(m_run[r] - mn);
      m_run[r] = mn;
      float rs = 0.0f;
#pragma unroll
      for (int nk = 0; nk < 4; ++nk) {
        const float p = __expf(s[nk][r] * 0.125f - mn);
        s[nk][r] = p;
        rs += p;
      }
#pragma unroll
      for (int off = 1; off < 16; off <<= 1) rs += __shfl_xor(rs, off);
      l_run[r] = l_run[r] * alpha + rs;
#pragma unroll
      for (int nd = 0; nd < 4; ++nd) o[nd][r] *= alpha;
    }

    // P -> per-wave LDS (bf16)
#pragma unroll
    for (int nk = 0; nk < 4; ++nk)
#pragma unroll
      for (int r = 0; r < 4; ++r) {
        const int q = g * 4 + r;
        *(u16*)(Pw + q * 128 + ((nk * 32 + li * 2) ^ (g << 5))) = f2bf(s[nk][r]);
      }
    asm volatile("s_waitcnt lgkmcnt(0)" ::: "memory");

    // O += P V   (A=P 16x32 from LDS, B=V 32x16 from transposed Vt)
#pragma unroll
    for (int ks = 0; ks < 2; ++ks) {
      const s16x8 pf = *(const s16x8*)(Pw + li * 128 + ((ks * 64 + 16 * g) ^ (((li >> 2) & 3) << 5)));
#pragma unroll
      for (int nd = 0; nd < 4; ++nd) {
        const int d = nd * 16 + li;
        const s16x8 vf = *(const s16x8*)((char*)Vt + d * 128 + ((ks * 64 + 16 * g) ^ (((d ^ (d >> 3)) & 7) << 4)));
        o[nd] = __builtin_amdgcn_mfma_f32_16x16x32_bf16(pf, vf, o[nd], 0, 0, 0);
      }
    }
  }

  // epilogue: normalize and store bf16
#pragma unroll
  for (int nd = 0; nd < 4; ++nd)
#pragma unroll
    for (int r = 0; r < 4; ++r) {
      const float v = o[nd][r] / l_run[r];
      const size_t row = baserow + qt * 64 + w * 16 + g * 4 + r;
      outp[row * 1024 + h * 64 + nd * 16 + li] = f2bf(v);
    }
}

// ---------------- launcher ----------------
extern "C" void kernel_launch(void* const* d_in, const int* in_sizes, int n_in,
                              void* d_out, int out_size, void* d_ws, size_t ws_size,
                              hipStream_t stream)
{
  const float* x     = (const float*)d_in[0];
  const float* gamma = (const float*)d_in[1];
  const float* beta  = (const float*)d_in[2];
  const float* Wqkv  = (const float*)d_in[3];
  const float* bqkv  = (const float*)d_in[4];
  const float* Wout  = (const float*)d_in[5];
  const float* bout  = (const float*)d_in[6];
  float* out = (float*)d_out;

  char* ws = (char*)d_ws;
  u16* xn     = (u16*)(ws);                       // 8 MB  [4096][1024]
  u16* wqkv_t = (u16*)(ws + ((size_t)8  << 20));  // 6 MB  [3072][1024]
  u16* wout_t = (u16*)(ws + ((size_t)14 << 20));  // 2 MB  [1024][1024]
  u16* qkv    = (u16*)(ws + ((size_t)16 << 20));  // 24 MB [4096][3072]
  u16* attn   = (u16*)(ws + ((size_t)40 << 20));  // 8 MB  [4096][1024]

  ln_kernel<<<4096, 256, 0, stream>>>(x, gamma, beta, xn);
  transpose_cvt<<<dim3(96, 32), dim3(32, 8), 0, stream>>>(Wqkv, wqkv_t, 1024, 3072);
  transpose_cvt<<<dim3(32, 32), dim3(32, 8), 0, stream>>>(Wout, wout_t, 1024, 1024);
  gemm_bt<u16><<<dim3(24, 32), 256, 0, stream>>>(xn, wqkv_t, bqkv, qkv, 4096, 3072, 1024);
  attn_kernel<<<1024, 256, 0, stream>>>(qkv, attn);
  gemm_bt<float><<<dim3(8, 32), 256, 0, stream>>>(attn, wout_t, bout, out, 4096, 1024, 1024);
}

// Round 7
// 210.516 us; speedup vs baseline: 1.0485x; 1.0485x over previous
//
#include <hip/hip_runtime.h>

typedef unsigned short u16;
typedef unsigned int   u32;
typedef __attribute__((ext_vector_type(4)))  float  f32x4;
typedef __attribute__((ext_vector_type(8)))  short  s16x8;

__device__ __forceinline__ u16 f2bf(float f) {
  unsigned u = __builtin_bit_cast(unsigned, f);
  u += 0x7FFFu + ((u >> 16) & 1u);
  return (u16)(u >> 16);
}

__device__ __forceinline__ void gload16(const void* g, void* l) {
  __builtin_amdgcn_global_load_lds(
      (const __attribute__((address_space(1))) void*)g,
      (__attribute__((address_space(3))) void*)l, 16, 0, 0);
}

// ---------------- LayerNorm (fp32 in -> bf16 out) ----------------
__global__ __launch_bounds__(256) void ln_kernel(
    const float* __restrict__ x, const float* __restrict__ gamma,
    const float* __restrict__ beta, u16* __restrict__ xn)
{
  const int row = blockIdx.x, tid = threadIdx.x;
  const float* xr = x + (size_t)row * 1024;
  float4 v = *(const float4*)(xr + tid * 4);
  float s  = v.x + v.y + v.z + v.w;
  float s2 = v.x*v.x + v.y*v.y + v.z*v.z + v.w*v.w;
#pragma unroll
  for (int off = 32; off >= 1; off >>= 1) {
    s  += __shfl_xor(s,  off);
    s2 += __shfl_xor(s2, off);
  }
  __shared__ float red[8];
  const int w = tid >> 6, l = tid & 63;
  if (l == 0) { red[w] = s; red[w + 4] = s2; }
  __syncthreads();
  s  = red[0] + red[1] + red[2] + red[3];
  s2 = red[4] + red[5] + red[6] + red[7];
  const float mu  = s * (1.0f / 1024.0f);
  const float var = s2 * (1.0f / 1024.0f) - mu * mu;
  const float rs  = rsqrtf(var + 1e-5f);
  float4 g  = *(const float4*)(gamma + tid * 4);
  float4 be = *(const float4*)(beta  + tid * 4);
  ushort4 o;
  o.x = f2bf((v.x - mu) * rs * g.x + be.x);
  o.y = f2bf((v.y - mu) * rs * g.y + be.y);
  o.z = f2bf((v.z - mu) * rs * g.z + be.z);
  o.w = f2bf((v.w - mu) * rs * g.w + be.w);
  *(ushort4*)(xn + (size_t)row * 1024 + tid * 4) = o;
}

// ---------------- transpose + fp32->bf16 convert ----------------
__global__ void transpose_cvt(const float* __restrict__ in, u16* __restrict__ out,
                              int R, int C)
{
  __shared__ float t[32][33];
  const int bc = blockIdx.x * 32, br = blockIdx.y * 32;
  const int x = threadIdx.x;
#pragma unroll
  for (int i = threadIdx.y; i < 32; i += 8)
    t[i][x] = in[(size_t)(br + i) * C + bc + x];
  __syncthreads();
#pragma unroll
  for (int i = threadIdx.y; i < 32; i += 8)
    out[(size_t)(bc + i) * R + br + x] = f2bf(t[x][i]);
}

// ---------------- GEMM: C[M][N] = A[M][K] * Bt[N][K]^T + bias ----------------
__device__ __forceinline__ void store_out(float* p, float v) { *p = v; }
__device__ __forceinline__ void store_out(u16* p, float v)   { *p = f2bf(v); }

template <typename OutT>
__global__ __launch_bounds__(256) void gemm_bt(
    const u16* __restrict__ A, const u16* __restrict__ Bt,
    const float* __restrict__ bias, OutT* __restrict__ C,
    int M, int N, int K)
{
  __shared__ u16 As[128 * 32];
  __shared__ u16 Bs[128 * 32];
  const int tid = threadIdx.x;
  const int w = tid >> 6, l = tid & 63;
  const int g = l >> 4, li = l & 15;
  const int bm = blockIdx.y * 128, bn = blockIdx.x * 128;
  const int wr = (w >> 1) * 64, wc = (w & 1) * 64;

  f32x4 acc[4][4] = {};

  const int ar0 = tid >> 2,          as0 = tid & 3;
  const int ar1 = (tid + 256) >> 2,  as1 = (tid + 256) & 3;
  const u16* pa0 = A  + (size_t)(bm + ar0) * K + 8 * (as0 ^ (ar0 & 3));
  const u16* pa1 = A  + (size_t)(bm + ar1) * K + 8 * (as1 ^ (ar1 & 3));
  const u16* pb0 = Bt + (size_t)(bn + ar0) * K + 8 * (as0 ^ (ar0 & 3));
  const u16* pb1 = Bt + (size_t)(bn + ar1) * K + 8 * (as1 ^ (ar1 & 3));
  u16* la0 = As + w * 512;
  u16* la1 = As + 2048 + w * 512;
  u16* lb0 = Bs + w * 512;
  u16* lb1 = Bs + 2048 + w * 512;

  for (int kt = 0; kt < K; kt += 32) {
    gload16(pa0 + kt, la0);
    gload16(pa1 + kt, la1);
    gload16(pb0 + kt, lb0);
    gload16(pb1 + kt, lb1);
    __syncthreads();

    s16x8 af[4], bf[4];
#pragma unroll
    for (int m = 0; m < 4; ++m) {
      const int row = wr + m * 16 + li;
      af[m] = *(const s16x8*)(As + row * 32 + 8 * (g ^ (row & 3)));
    }
#pragma unroll
    for (int n = 0; n < 4; ++n) {
      const int row = wc + n * 16 + li;
      bf[n] = *(const s16x8*)(Bs + row * 32 + 8 * (g ^ (row & 3)));
    }
#pragma unroll
    for (int m = 0; m < 4; ++m)
#pragma unroll
      for (int n = 0; n < 4; ++n)
        acc[m][n] = __builtin_amdgcn_mfma_f32_16x16x32_bf16(af[m], bf[n], acc[m][n], 0, 0, 0);
    __syncthreads();
  }

#pragma unroll
  for (int n = 0; n < 4; ++n) {
    const int col = bn + wc + n * 16 + li;
    const float bv = bias[col];
#pragma unroll
    for (int m = 0; m < 4; ++m) {
      const int row0 = bm + wr + m * 16 + g * 4;
#pragma unroll
      for (int r = 0; r < 4; ++r)
        store_out(C + (size_t)(row0 + r) * N + col, acc[m][n][r] + bv);
    }
  }
}

// ---------------- flash attention (r1 structure + dbuf/T14/T13/T5/T1) ----------------
// qkv: [4096][3072] bf16, q|k|v each [.,1024] with head h at cols h*64..h*64+63
// out: [4096][1024] bf16
__global__ __launch_bounds__(256) void attn_kernel(
    const u16* __restrict__ qkv, u16* __restrict__ outp)
{
  __shared__ u16 Ks[2][4096];      // [kv][d], 16B chunks XOR-swizzled by (kv&7)  (r1-verified)
  __shared__ u16 Vt[2][4096];      // [d][kv], byte XOR-swizzle ((d^(d>>3))&7)<<4 (r1-verified)
  __shared__ u16 Pl[4 * 16 * 64];  // per-wave P[q][kv], swizzled by (g<<5)       (r1-verified)

  const int tid = threadIdx.x;
  const int w = tid >> 6, l = tid & 63;
  const int g = l >> 4, li = l & 15;

  // T1: bijective XCD swizzle (1024 = 8 * 128); keeps the 32 qt-blocks sharing
  // one (h,b) K/V panel on the same XCD's L2.
  const int lb = (blockIdx.x & 7) * 128 + (blockIdx.x >> 3);
  const int qt = lb & 31;
  const int h  = (lb >> 5) & 15;
  const int bb = lb >> 9;
  const size_t baserow = (size_t)bb * 2048;

  // hoisted Q fragments: Q[q=li][d = ks*32 + 8g + j]
  const size_t qrow = baserow + qt * 64 + w * 16 + li;
  const u16* qp = qkv + qrow * 3072 + h * 64 + 8 * g;
  const s16x8 qf0 = *(const s16x8*)(qp);
  const s16x8 qf1 = *(const s16x8*)(qp + 32);

  // K staging (r1-verified): 512 chunks; chunk c -> kv c>>3, slot c&7, pre-swizzled source
  const int kr0 = tid >> 3,         kc0 = tid & 7;
  const int kr1 = (tid + 256) >> 3, kc1 = (tid + 256) & 7;
  const u16* kg0 = qkv + (baserow + kr0) * 3072 + 1024 + h * 64 + 8 * (kc0 ^ (kr0 & 7));
  const u16* kg1 = qkv + (baserow + kr1) * 3072 + 1024 + h * 64 + 8 * (kc1 ^ (kr1 & 7));

  // V reg-staging: thread owns kv-pair p (0..31) x d-group dg (0..7)
  const int vp = tid >> 3, dg = tid & 7;
  const u16* vgA = qkv + (baserow + 2 * vp)     * 3072 + 2048 + h * 64 + 8 * dg;
  const u16* vgB = qkv + (baserow + 2 * vp + 1) * 3072 + 2048 + h * 64 + 8 * dg;

  auto issueK = [&](int b, int t) {
    const size_t koff = (size_t)t * (64 * 3072);
    gload16(kg0 + koff, &Ks[b][w * 512]);
    gload16(kg1 + koff, &Ks[b][2048 + w * 512]);
  };

  float m_run[4], l_run[4];
  f32x4 o[4] = {};
#pragma unroll
  for (int r = 0; r < 4; ++r) { m_run[r] = -1e30f; l_run[r] = 0.0f; }

  char* Pw = (char*)(Pl + w * 1024);

  // prologue: prefetch tile 0
  issueK(0, 0);
  s16x8 va = *(const s16x8*)vgA;
  s16x8 vb = *(const s16x8*)vgB;

  int buf = 0;
  for (int t = 0; t < 32; ++t) {
    // write V regs (tile t) -> Vt[buf]; paired kv per b32 write, same swizzle
    // involution as the r1-verified read side.
#pragma unroll
    for (int j = 0; j < 8; ++j) {
      const int d = 8 * dg + j;
      const u32 val = (u32)(u16)va[j] | ((u32)(u16)vb[j] << 16);
      *(u32*)((char*)&Vt[buf][0] + d * 128 + ((4 * vp) ^ ((((d ^ (d >> 3)) & 7)) << 4))) = val;
    }
    __syncthreads();   // drains K gload for buf; Vt[buf] visible

    if (t < 31) {      // T14: issue next tile's loads before compute
      issueK(buf ^ 1, t + 1);
      const size_t koff = (size_t)(t + 1) * (64 * 3072);
      va = *(const s16x8*)(vgA + koff);
      vb = *(const s16x8*)(vgB + koff);
    }

    const u16* kb = &Ks[buf][0];

    // S = Q K^T (r1-verified fragment indexing)
    f32x4 s[4] = {};
    __builtin_amdgcn_s_setprio(1);
#pragma unroll
    for (int nk = 0; nk < 4; ++nk) {
      const int kvr = nk * 16 + li;
      const s16x8 kf0 = *(const s16x8*)((const char*)kb + kvr * 128 + 16 * ((0 + g) ^ (kvr & 7)));
      const s16x8 kf1 = *(const s16x8*)((const char*)kb + kvr * 128 + 16 * ((4 + g) ^ (kvr & 7)));
      s[nk] = __builtin_amdgcn_mfma_f32_16x16x32_bf16(qf0, kf0, s[nk], 0, 0, 0);
      s[nk] = __builtin_amdgcn_mfma_f32_16x16x32_bf16(qf1, kf1, s[nk], 0, 0, 0);
    }
    __builtin_amdgcn_s_setprio(0);

    // online softmax with defer-max (T13): lane-local check, rescale only on growth
    float lmx[4];
    bool need = false;
#pragma unroll
    for (int r = 0; r < 4; ++r) {
      lmx[r] = fmaxf(fmaxf(s[0][r], s[1][r]), fmaxf(s[2][r], s[3][r])) * 0.125f;
      need |= (lmx[r] > m_run[r] + 8.0f);
    }
    if (__any(need)) {
#pragma unroll
      for (int r = 0; r < 4; ++r) {
        float mx = lmx[r];
#pragma unroll
        for (int off = 1; off < 16; off <<= 1) mx = fmaxf(mx, __shfl_xor(mx, off));
        const float mn = fmaxf(m_run[r], mx);
        const float alpha = __expf(m_run[r] - mn);
        m_run[r] = mn;
        l_run[r] *= alpha;
#pragma unroll
        for (int nd = 0; nd < 4; ++nd) o[nd][r] *= alpha;
      }
    }
#pragma unroll
    for (int r = 0; r < 4; ++r) {
      float rs = 0.0f;
#pragma unroll
      for (int nk = 0; nk < 4; ++nk) {
        const float p = __expf(fmaf(s[nk][r], 0.125f, -m_run[r]));
        s[nk][r] = p;
        rs += p;
      }
#pragma unroll
      for (int off = 1; off < 16; off <<= 1) rs += __shfl_xor(rs, off);
      l_run[r] += rs;
    }

    // P -> per-wave LDS (r1-verified)
#pragma unroll
    for (int nk = 0; nk < 4; ++nk)
#pragma unroll
      for (int r = 0; r < 4; ++r) {
        const int q = g * 4 + r;
        *(u16*)(Pw + q * 128 + ((nk * 32 + li * 2) ^ (g << 5))) = f2bf(s[nk][r]);
      }
    asm volatile("s_waitcnt lgkmcnt(0)" ::: "memory");

    // O += P V (r1-verified)
    __builtin_amdgcn_s_setprio(1);
#pragma unroll
    for (int ks = 0; ks < 2; ++ks) {
      const s16x8 pf = *(const s16x8*)(Pw + li * 128 + ((ks * 64 + 16 * g) ^ (((li >> 2) & 3) << 5)));
#pragma unroll
      for (int nd = 0; nd < 4; ++nd) {
        const int d = nd * 16 + li;
        const s16x8 vf = *(const s16x8*)((char*)&Vt[buf][0] + d * 128 + ((ks * 64 + 16 * g) ^ (((d ^ (d >> 3)) & 7) << 4)));
        o[nd] = __builtin_amdgcn_mfma_f32_16x16x32_bf16(pf, vf, o[nd], 0, 0, 0);
      }
    }
    __builtin_amdgcn_s_setprio(0);

    __syncthreads();   // all waves done reading buf (prefetch drains here too)
    buf ^= 1;
  }

  // epilogue: normalize and store bf16 (r1-verified)
#pragma unroll
  for (int nd = 0; nd < 4; ++nd)
#pragma unroll
    for (int r = 0; r < 4; ++r) {
      const float v = o[nd][r] / l_run[r];
      const size_t row = baserow + qt * 64 + w * 16 + g * 4 + r;
      outp[row * 1024 + h * 64 + nd * 16 + li] = f2bf(v);
    }
}

// ---------------- launcher ----------------
extern "C" void kernel_launch(void* const* d_in, const int* in_sizes, int n_in,
                              void* d_out, int out_size, void* d_ws, size_t ws_size,
                              hipStream_t stream)
{
  const float* x     = (const float*)d_in[0];
  const float* gamma = (const float*)d_in[1];
  const float* beta  = (const float*)d_in[2];
  const float* Wqkv  = (const float*)d_in[3];
  const float* bqkv  = (const float*)d_in[4];
  const float* Wout  = (const float*)d_in[5];
  const float* bout  = (const float*)d_in[6];
  float* out = (float*)d_out;

  char* ws = (char*)d_ws;
  u16* xn     = (u16*)(ws);                       // 8 MB  [4096][1024]
  u16* wqkv_t = (u16*)(ws + ((size_t)8  << 20));  // 6 MB  [3072][1024]
  u16* wout_t = (u16*)(ws + ((size_t)14 << 20));  // 2 MB  [1024][1024]
  u16* qkv    = (u16*)(ws + ((size_t)16 << 20));  // 24 MB [4096][3072]
  u16* attn   = (u16*)(ws + ((size_t)40 << 20));  // 8 MB  [4096][1024]

  ln_kernel<<<4096, 256, 0, stream>>>(x, gamma, beta, xn);
  transpose_cvt<<<dim3(96, 32), dim3(32, 8), 0, stream>>>(Wqkv, wqkv_t, 1024, 3072);
  transpose_cvt<<<dim3(32, 32), dim3(32, 8), 0, stream>>>(Wout, wout_t, 1024, 1024);
  gemm_bt<u16><<<dim3(24, 32), 256, 0, stream>>>(xn, wqkv_t, bqkv, qkv, 4096, 3072, 1024);
  attn_kernel<<<1024, 256, 0, stream>>>(qkv, attn);
  gemm_bt<float><<<dim3(8, 32), 256, 0, stream>>>(attn, wout_t, bout, out, 4096, 1024, 1024);
}

// Round 9
// 170.112 us; speedup vs baseline: 1.2975x; 1.2375x over previous
//
#include <hip/hip_runtime.h>

typedef unsigned short u16;
typedef unsigned int   u32;
typedef __attribute__((ext_vector_type(4)))  float  f32x4;
typedef __attribute__((ext_vector_type(8)))  short  s16x8;

__device__ __forceinline__ u16 f2bf(float f) {
  unsigned u = __builtin_bit_cast(unsigned, f);
  u += 0x7FFFu + ((u >> 16) & 1u);
  return (u16)(u >> 16);
}

__device__ __forceinline__ float exp2g(float x) { return __builtin_amdgcn_exp2f(x); }

__device__ __forceinline__ void gload16(const void* g, void* l) {
  __builtin_amdgcn_global_load_lds(
      (const __attribute__((address_space(1))) void*)g,
      (__attribute__((address_space(3))) void*)l, 16, 0, 0);
}

// ---------------- LayerNorm (fp32 in -> bf16 out) ----------------
__global__ __launch_bounds__(256) void ln_kernel(
    const float* __restrict__ x, const float* __restrict__ gamma,
    const float* __restrict__ beta, u16* __restrict__ xn)
{
  const int row = blockIdx.x, tid = threadIdx.x;
  const float* xr = x + (size_t)row * 1024;
  float4 v = *(const float4*)(xr + tid * 4);
  float s  = v.x + v.y + v.z + v.w;
  float s2 = v.x*v.x + v.y*v.y + v.z*v.z + v.w*v.w;
#pragma unroll
  for (int off = 32; off >= 1; off >>= 1) {
    s  += __shfl_xor(s,  off);
    s2 += __shfl_xor(s2, off);
  }
  __shared__ float red[8];
  const int w = tid >> 6, l = tid & 63;
  if (l == 0) { red[w] = s; red[w + 4] = s2; }
  __syncthreads();
  s  = red[0] + red[1] + red[2] + red[3];
  s2 = red[4] + red[5] + red[6] + red[7];
  const float mu  = s * (1.0f / 1024.0f);
  const float var = s2 * (1.0f / 1024.0f) - mu * mu;
  const float rs  = rsqrtf(var + 1e-5f);
  float4 g  = *(const float4*)(gamma + tid * 4);
  float4 be = *(const float4*)(beta  + tid * 4);
  ushort4 o;
  o.x = f2bf((v.x - mu) * rs * g.x + be.x);
  o.y = f2bf((v.y - mu) * rs * g.y + be.y);
  o.z = f2bf((v.z - mu) * rs * g.z + be.z);
  o.w = f2bf((v.w - mu) * rs * g.w + be.w);
  *(ushort4*)(xn + (size_t)row * 1024 + tid * 4) = o;
}

// ---------------- transpose + fp32->bf16 convert ----------------
__global__ void transpose_cvt(const float* __restrict__ in, u16* __restrict__ out,
                              int R, int C)
{
  __shared__ float t[32][33];
  const int bc = blockIdx.x * 32, br = blockIdx.y * 32;
  const int x = threadIdx.x;
#pragma unroll
  for (int i = threadIdx.y; i < 32; i += 8)
    t[i][x] = in[(size_t)(br + i) * C + bc + x];
  __syncthreads();
#pragma unroll
  for (int i = threadIdx.y; i < 32; i += 8)
    out[(size_t)(bc + i) * R + br + x] = f2bf(t[x][i]);
}

// ---------------- GEMM: C[M][N] = A[M][K] * Bt[N][K]^T + bias ----------------
__device__ __forceinline__ void store_out(float* p, float v) { *p = v; }
__device__ __forceinline__ void store_out(u16* p, float v)   { *p = f2bf(v); }

template <typename OutT>
__global__ __launch_bounds__(256) void gemm_bt(
    const u16* __restrict__ A, const u16* __restrict__ Bt,
    const float* __restrict__ bias, OutT* __restrict__ C,
    int M, int N, int K)
{
  __shared__ u16 As[128 * 32];
  __shared__ u16 Bs[128 * 32];
  const int tid = threadIdx.x;
  const int w = tid >> 6, l = tid & 63;
  const int g = l >> 4, li = l & 15;
  const int bm = blockIdx.y * 128, bn = blockIdx.x * 128;
  const int wr = (w >> 1) * 64, wc = (w & 1) * 64;

  f32x4 acc[4][4] = {};

  const int ar0 = tid >> 2,          as0 = tid & 3;
  const int ar1 = (tid + 256) >> 2,  as1 = (tid + 256) & 3;
  const u16* pa0 = A  + (size_t)(bm + ar0) * K + 8 * (as0 ^ (ar0 & 3));
  const u16* pa1 = A  + (size_t)(bm + ar1) * K + 8 * (as1 ^ (ar1 & 3));
  const u16* pb0 = Bt + (size_t)(bn + ar0) * K + 8 * (as0 ^ (ar0 & 3));
  const u16* pb1 = Bt + (size_t)(bn + ar1) * K + 8 * (as1 ^ (ar1 & 3));
  u16* la0 = As + w * 512;
  u16* la1 = As + 2048 + w * 512;
  u16* lb0 = Bs + w * 512;
  u16* lb1 = Bs + 2048 + w * 512;

  for (int kt = 0; kt < K; kt += 32) {
    gload16(pa0 + kt, la0);
    gload16(pa1 + kt, la1);
    gload16(pb0 + kt, lb0);
    gload16(pb1 + kt, lb1);
    __syncthreads();

    s16x8 af[4], bf[4];
#pragma unroll
    for (int m = 0; m < 4; ++m) {
      const int row = wr + m * 16 + li;
      af[m] = *(const s16x8*)(As + row * 32 + 8 * (g ^ (row & 3)));
    }
#pragma unroll
    for (int n = 0; n < 4; ++n) {
      const int row = wc + n * 16 + li;
      bf[n] = *(const s16x8*)(Bs + row * 32 + 8 * (g ^ (row & 3)));
    }
#pragma unroll
    for (int m = 0; m < 4; ++m)
#pragma unroll
      for (int n = 0; n < 4; ++n)
        acc[m][n] = __builtin_amdgcn_mfma_f32_16x16x32_bf16(af[m], bf[n], acc[m][n], 0, 0, 0);
    __syncthreads();
  }

#pragma unroll
  for (int n = 0; n < 4; ++n) {
    const int col = bn + wc + n * 16 + li;
    const float bv = bias[col];
#pragma unroll
    for (int m = 0; m < 4; ++m) {
      const int row0 = bm + wr + m * 16 + g * 4;
#pragma unroll
      for (int r = 0; r < 4; ++r)
        store_out(C + (size_t)(row0 + r) * N + col, acc[m][n][r] + bv);
    }
  }
}

// ---------------- flash attention: 32 q-rows/wave, ones-col rowsum ----------------
// qkv: [4096][3072] bf16, q|k|v each [.,1024] with head h at cols h*64..h*64+63
// out: [4096][1024] bf16
// grid 512 (16 qt x 16 h x 2 b); block = 4 waves; each wave owns 2x16 q-rows.
__global__ __launch_bounds__(256, 2) void attn_kernel(
    const u16* __restrict__ qkv, u16* __restrict__ outp)
{
  __shared__ u16 Ks[2][4096];   // [kv][d] dbuf, 16B chunks XOR-swizzled by (kv&7)  (verified)
  __shared__ u16 Vt[4096];      // [d][kv] single, byte XOR ((d^(d>>3))&7)<<4       (verified)
  __shared__ u16 Pl[4 * 1024];  // per-wave P[16q][64kv], swizzled by (g<<5)        (verified)

  const int tid = threadIdx.x;
  const int w = tid >> 6, l = tid & 63;
  const int g = l >> 4, li = l & 15;

  // T1: bijective XCD swizzle (512 = 8 * 64)
  const int lb = (blockIdx.x & 7) * 64 + (blockIdx.x >> 3);
  const int qt = lb & 15;
  const int h  = (lb >> 4) & 15;
  const int bb = lb >> 8;
  const size_t baserow = (size_t)bb * 2048;

  // hoisted Q fragments for both 16-row blocks (A: rows qt*128+w*16, B: +64)
  const int qbaseA = qt * 128 + w * 16;
  const u16* qpA = qkv + (baserow + qbaseA + li) * 3072 + h * 64 + 8 * g;
  const u16* qpB = qpA + (size_t)64 * 3072;
  const s16x8 qfA0 = *(const s16x8*)(qpA);
  const s16x8 qfA1 = *(const s16x8*)(qpA + 32);
  const s16x8 qfB0 = *(const s16x8*)(qpB);
  const s16x8 qfB1 = *(const s16x8*)(qpB + 32);

  // K staging (verified): chunk c -> kv c>>3, slot c&7, pre-swizzled source
  const int kr0 = tid >> 3,         kc0 = tid & 7;
  const int kr1 = (tid + 256) >> 3, kc1 = (tid + 256) & 7;
  const u16* kg0 = qkv + (baserow + kr0) * 3072 + 1024 + h * 64 + 8 * (kc0 ^ (kr0 & 7));
  const u16* kg1 = qkv + (baserow + kr1) * 3072 + 1024 + h * 64 + 8 * (kc1 ^ (kr1 & 7));

  // V reg-staging: thread owns kv-pair vp x d-group dg
  const int vp = tid >> 3, dg = tid & 7;
  const u16* vgA = qkv + (baserow + 2 * vp)     * 3072 + 2048 + h * 64 + 8 * dg;
  const u16* vgB = qkv + (baserow + 2 * vp + 1) * 3072 + 2048 + h * 64 + 8 * dg;

  auto issueK = [&](int b, int t) {
    const size_t koff = (size_t)t * (64 * 3072);
    gload16(kg0 + koff, &Ks[b][w * 512]);
    gload16(kg1 + koff, &Ks[b][2048 + w * 512]);
  };

  // log2-domain online softmax state (M = m * log2e); rowsum via ones-column MFMA
  const float C1  = 0.18033688f;   // 0.125 * log2(e)
  const float THR = 11.5416f;      // 8 * log2(e)
  float MA[4], MB[4];
#pragma unroll
  for (int r = 0; r < 4; ++r) { MA[r] = -1e30f; MB[r] = -1e30f; }
  f32x4 oA[4] = {}, oB[4] = {}, osA = {}, osB = {};

  s16x8 ones;
#pragma unroll
  for (int j = 0; j < 8; ++j) ones[j] = (short)0x3F80;   // bf16 1.0

  char* Pw = (char*)(Pl + w * 1024);

  // prologue: prefetch tile 0
  issueK(0, 0);
  s16x8 va = *(const s16x8*)vgA;
  s16x8 vb = *(const s16x8*)vgB;

  int buf = 0;
  for (int t = 0; t < 32; ++t) {
    // V regs (tile t) -> Vt; paired-kv b32 writes, verified swizzle involution
#pragma unroll
    for (int j = 0; j < 8; ++j) {
      const int d = 8 * dg + j;
      const u32 val = (u32)(u16)va[j] | ((u32)(u16)vb[j] << 16);
      *(u32*)((char*)Vt + d * 128 + ((4 * vp) ^ ((((d ^ (d >> 3)) & 7)) << 4))) = val;
    }
    __syncthreads();   // K[buf] gload drained; Vt visible

    if (t < 31) {      // prefetch next tile
      issueK(buf ^ 1, t + 1);
      const size_t koff = (size_t)(t + 1) * (64 * 3072);
      va = *(const s16x8*)(vgA + koff);
      vb = *(const s16x8*)(vgB + koff);
    }

    const u16* kb = &Ks[buf][0];

    // ---- S = Q K^T for both q-blocks; 8 ds_read serve 16 MFMA ----
    f32x4 sA[4] = {}, sB[4] = {};
    __builtin_amdgcn_s_setprio(1);
#pragma unroll
    for (int nk = 0; nk < 4; ++nk) {
      const int kvr = nk * 16 + li;
      const s16x8 kf0 = *(const s16x8*)((const char*)kb + kvr * 128 + 16 * ((0 + g) ^ (kvr & 7)));
      const s16x8 kf1 = *(const s16x8*)((const char*)kb + kvr * 128 + 16 * ((4 + g) ^ (kvr & 7)));
      sA[nk] = __builtin_amdgcn_mfma_f32_16x16x32_bf16(qfA0, kf0, sA[nk], 0, 0, 0);
      sA[nk] = __builtin_amdgcn_mfma_f32_16x16x32_bf16(qfA1, kf1, sA[nk], 0, 0, 0);
      sB[nk] = __builtin_amdgcn_mfma_f32_16x16x32_bf16(qfB0, kf0, sB[nk], 0, 0, 0);
      sB[nk] = __builtin_amdgcn_mfma_f32_16x16x32_bf16(qfB1, kf1, sB[nk], 0, 0, 0);
    }
    __builtin_amdgcn_s_setprio(0);

    // ---- defer-max (T13): lane-local check; rare full rescale ----
    float lmA[4], lmB[4];
    bool need = false;
#pragma unroll
    for (int r = 0; r < 4; ++r) {
      lmA[r] = fmaxf(fmaxf(sA[0][r], sA[1][r]), fmaxf(sA[2][r], sA[3][r])) * C1;
      lmB[r] = fmaxf(fmaxf(sB[0][r], sB[1][r]), fmaxf(sB[2][r], sB[3][r])) * C1;
      need |= (lmA[r] > MA[r] + THR) | (lmB[r] > MB[r] + THR);
    }
    if (__any(need)) {
#pragma unroll
      for (int r = 0; r < 4; ++r) {
        float mxA = lmA[r], mxB = lmB[r];
#pragma unroll
        for (int off = 1; off < 16; off <<= 1) {
          mxA = fmaxf(mxA, __shfl_xor(mxA, off));
          mxB = fmaxf(mxB, __shfl_xor(mxB, off));
        }
        const float mnA = fmaxf(MA[r], mxA);
        const float mnB = fmaxf(MB[r], mxB);
        const float aA = exp2g(MA[r] - mnA);
        const float aB = exp2g(MB[r] - mnB);
        MA[r] = mnA; MB[r] = mnB;
        osA[r] *= aA; osB[r] *= aB;
#pragma unroll
        for (int nd = 0; nd < 4; ++nd) { oA[nd][r] *= aA; oB[nd][r] *= aB; }
      }
    }

    // ---- exp2 in place (P values, bounded by 2^THR) ----
#pragma unroll
    for (int r = 0; r < 4; ++r) {
#pragma unroll
      for (int nk = 0; nk < 4; ++nk) {
        sA[nk][r] = exp2g(fmaf(sA[nk][r], C1, -MA[r]));
        sB[nk][r] = exp2g(fmaf(sB[nk][r], C1, -MB[r]));
      }
    }

    // ---- block A: P -> LDS, PV + ones-column rowsum ----
#pragma unroll
    for (int nk = 0; nk < 4; ++nk)
#pragma unroll
      for (int r = 0; r < 4; ++r) {
        const int q = g * 4 + r;
        *(u16*)(Pw + q * 128 + ((nk * 32 + li * 2) ^ (g << 5))) = f2bf(sA[nk][r]);
      }
    asm volatile("s_waitcnt lgkmcnt(0)" ::: "memory");

    __builtin_amdgcn_s_setprio(1);
#pragma unroll
    for (int ks = 0; ks < 2; ++ks) {
      const s16x8 pf = *(const s16x8*)(Pw + li * 128 + ((ks * 64 + 16 * g) ^ (((li >> 2) & 3) << 5)));
#pragma unroll
      for (int nd = 0; nd < 4; ++nd) {
        const int d = nd * 16 + li;
        const s16x8 vf = *(const s16x8*)((char*)Vt + d * 128 + ((ks * 64 + 16 * g) ^ (((d ^ (d >> 3)) & 7) << 4)));
        oA[nd] = __builtin_amdgcn_mfma_f32_16x16x32_bf16(pf, vf, oA[nd], 0, 0, 0);
      }
      osA = __builtin_amdgcn_mfma_f32_16x16x32_bf16(pf, ones, osA, 0, 0, 0);
    }
    __builtin_amdgcn_s_setprio(0);
    asm volatile("s_waitcnt lgkmcnt(0)" ::: "memory");  // pf_A reads drained before overwrite

    // ---- block B: reuse the same P region ----
#pragma unroll
    for (int nk = 0; nk < 4; ++nk)
#pragma unroll
      for (int r = 0; r < 4; ++r) {
        const int q = g * 4 + r;
        *(u16*)(Pw + q * 128 + ((nk * 32 + li * 2) ^ (g << 5))) = f2bf(sB[nk][r]);
      }
    asm volatile("s_waitcnt lgkmcnt(0)" ::: "memory");

    __builtin_amdgcn_s_setprio(1);
#pragma unroll
    for (int ks = 0; ks < 2; ++ks) {
      const s16x8 pf = *(const s16x8*)(Pw + li * 128 + ((ks * 64 + 16 * g) ^ (((li >> 2) & 3) << 5)));
#pragma unroll
      for (int nd = 0; nd < 4; ++nd) {
        const int d = nd * 16 + li;
        const s16x8 vf = *(const s16x8*)((char*)Vt + d * 128 + ((ks * 64 + 16 * g) ^ (((d ^ (d >> 3)) & 7) << 4)));
        oB[nd] = __builtin_amdgcn_mfma_f32_16x16x32_bf16(pf, vf, oB[nd], 0, 0, 0);
      }
      osB = __builtin_amdgcn_mfma_f32_16x16x32_bf16(pf, ones, osB, 0, 0, 0);
    }
    __builtin_amdgcn_s_setprio(0);

    __syncthreads();   // all waves done with Ks[buf], Vt, prefetch drained
    buf ^= 1;
  }

  // ---- epilogue: normalize by ones-column rowsum, store bf16 ----
#pragma unroll
  for (int r = 0; r < 4; ++r) {
    const float invA = 1.0f / osA[r];
    const float invB = 1.0f / osB[r];
    const size_t rowA = baserow + qbaseA + g * 4 + r;
#pragma unroll
    for (int nd = 0; nd < 4; ++nd) {
      outp[rowA * 1024 + h * 64 + nd * 16 + li]        = f2bf(oA[nd][r] * invA);
      outp[(rowA + 64) * 1024 + h * 64 + nd * 16 + li] = f2bf(oB[nd][r] * invB);
    }
  }
}

// ---------------- launcher ----------------
extern "C" void kernel_launch(void* const* d_in, const int* in_sizes, int n_in,
                              void* d_out, int out_size, void* d_ws, size_t ws_size,
                              hipStream_t stream)
{
  const float* x     = (const float*)d_in[0];
  const float* gamma = (const float*)d_in[1];
  const float* beta  = (const float*)d_in[2];
  const float* Wqkv  = (const float*)d_in[3];
  const float* bqkv  = (const float*)d_in[4];
  const float* Wout  = (const float*)d_in[5];
  const float* bout  = (const float*)d_in[6];
  float* out = (float*)d_out;

  char* ws = (char*)d_ws;
  u16* xn     = (u16*)(ws);                       // 8 MB  [4096][1024]
  u16* wqkv_t = (u16*)(ws + ((size_t)8  << 20));  // 6 MB  [3072][1024]
  u16* wout_t = (u16*)(ws + ((size_t)14 << 20));  // 2 MB  [1024][1024]
  u16* qkv    = (u16*)(ws + ((size_t)16 << 20));  // 24 MB [4096][3072]
  u16* attn   = (u16*)(ws + ((size_t)40 << 20));  // 8 MB  [4096][1024]

  ln_kernel<<<4096, 256, 0, stream>>>(x, gamma, beta, xn);
  transpose_cvt<<<dim3(96, 32), dim3(32, 8), 0, stream>>>(Wqkv, wqkv_t, 1024, 3072);
  transpose_cvt<<<dim3(32, 32), dim3(32, 8), 0, stream>>>(Wout, wout_t, 1024, 1024);
  gemm_bt<u16><<<dim3(24, 32), 256, 0, stream>>>(xn, wqkv_t, bqkv, qkv, 4096, 3072, 1024);
  attn_kernel<<<512, 256, 0, stream>>>(qkv, attn);
  gemm_bt<float><<<dim3(8, 32), 256, 0, stream>>>(attn, wout_t, bout, out, 4096, 1024, 1024);
}

// Round 10
// 166.336 us; speedup vs baseline: 1.3269x; 1.0227x over previous
//
#include <hip/hip_runtime.h>

typedef unsigned short u16;
typedef unsigned int   u32;
typedef __attribute__((ext_vector_type(4)))  float  f32x4;
typedef __attribute__((ext_vector_type(8)))  short  s16x8;

__device__ __forceinline__ u16 f2bf(float f) {
  unsigned u = __builtin_bit_cast(unsigned, f);
  u += 0x7FFFu + ((u >> 16) & 1u);
  return (u16)(u >> 16);
}

__device__ __forceinline__ float exp2g(float x) { return __builtin_amdgcn_exp2f(x); }

__device__ __forceinline__ void gload16(const void* g, void* l) {
  __builtin_amdgcn_global_load_lds(
      (const __attribute__((address_space(1))) void*)g,
      (__attribute__((address_space(3))) void*)l, 16, 0, 0);
}

// ---------------- LayerNorm (fp32 in -> bf16 out) ----------------
__global__ __launch_bounds__(256) void ln_kernel(
    const float* __restrict__ x, const float* __restrict__ gamma,
    const float* __restrict__ beta, u16* __restrict__ xn)
{
  const int row = blockIdx.x, tid = threadIdx.x;
  const float* xr = x + (size_t)row * 1024;
  float4 v = *(const float4*)(xr + tid * 4);
  float s  = v.x + v.y + v.z + v.w;
  float s2 = v.x*v.x + v.y*v.y + v.z*v.z + v.w*v.w;
#pragma unroll
  for (int off = 32; off >= 1; off >>= 1) {
    s  += __shfl_xor(s,  off);
    s2 += __shfl_xor(s2, off);
  }
  __shared__ float red[8];
  const int w = tid >> 6, l = tid & 63;
  if (l == 0) { red[w] = s; red[w + 4] = s2; }
  __syncthreads();
  s  = red[0] + red[1] + red[2] + red[3];
  s2 = red[4] + red[5] + red[6] + red[7];
  const float mu  = s * (1.0f / 1024.0f);
  const float var = s2 * (1.0f / 1024.0f) - mu * mu;
  const float rs  = rsqrtf(var + 1e-5f);
  float4 g  = *(const float4*)(gamma + tid * 4);
  float4 be = *(const float4*)(beta  + tid * 4);
  ushort4 o;
  o.x = f2bf((v.x - mu) * rs * g.x + be.x);
  o.y = f2bf((v.y - mu) * rs * g.y + be.y);
  o.z = f2bf((v.z - mu) * rs * g.z + be.z);
  o.w = f2bf((v.w - mu) * rs * g.w + be.w);
  *(ushort4*)(xn + (size_t)row * 1024 + tid * 4) = o;
}

// ---------------- transpose + fp32->bf16 convert ----------------
__global__ void transpose_cvt(const float* __restrict__ in, u16* __restrict__ out,
                              int R, int C)
{
  __shared__ float t[32][33];
  const int bc = blockIdx.x * 32, br = blockIdx.y * 32;
  const int x = threadIdx.x;
#pragma unroll
  for (int i = threadIdx.y; i < 32; i += 8)
    t[i][x] = in[(size_t)(br + i) * C + bc + x];
  __syncthreads();
#pragma unroll
  for (int i = threadIdx.y; i < 32; i += 8)
    out[(size_t)(bc + i) * R + br + x] = f2bf(t[x][i]);
}

// ---------------- GEMM: C[M][N] = A[M][K] * Bt[N][K]^T + bias ----------------
__device__ __forceinline__ void store_out(float* p, float v) { *p = v; }
__device__ __forceinline__ void store_out(u16* p, float v)   { *p = f2bf(v); }

template <typename OutT>
__global__ __launch_bounds__(256) void gemm_bt(
    const u16* __restrict__ A, const u16* __restrict__ Bt,
    const float* __restrict__ bias, OutT* __restrict__ C,
    int M, int N, int K)
{
  __shared__ u16 As[128 * 32];
  __shared__ u16 Bs[128 * 32];
  const int tid = threadIdx.x;
  const int w = tid >> 6, l = tid & 63;
  const int g = l >> 4, li = l & 15;
  const int bm = blockIdx.y * 128, bn = blockIdx.x * 128;
  const int wr = (w >> 1) * 64, wc = (w & 1) * 64;

  f32x4 acc[4][4] = {};

  const int ar0 = tid >> 2,          as0 = tid & 3;
  const int ar1 = (tid + 256) >> 2,  as1 = (tid + 256) & 3;
  const u16* pa0 = A  + (size_t)(bm + ar0) * K + 8 * (as0 ^ (ar0 & 3));
  const u16* pa1 = A  + (size_t)(bm + ar1) * K + 8 * (as1 ^ (ar1 & 3));
  const u16* pb0 = Bt + (size_t)(bn + ar0) * K + 8 * (as0 ^ (ar0 & 3));
  const u16* pb1 = Bt + (size_t)(bn + ar1) * K + 8 * (as1 ^ (ar1 & 3));
  u16* la0 = As + w * 512;
  u16* la1 = As + 2048 + w * 512;
  u16* lb0 = Bs + w * 512;
  u16* lb1 = Bs + 2048 + w * 512;

  for (int kt = 0; kt < K; kt += 32) {
    gload16(pa0 + kt, la0);
    gload16(pa1 + kt, la1);
    gload16(pb0 + kt, lb0);
    gload16(pb1 + kt, lb1);
    __syncthreads();

    s16x8 af[4], bf[4];
#pragma unroll
    for (int m = 0; m < 4; ++m) {
      const int row = wr + m * 16 + li;
      af[m] = *(const s16x8*)(As + row * 32 + 8 * (g ^ (row & 3)));
    }
#pragma unroll
    for (int n = 0; n < 4; ++n) {
      const int row = wc + n * 16 + li;
      bf[n] = *(const s16x8*)(Bs + row * 32 + 8 * (g ^ (row & 3)));
    }
#pragma unroll
    for (int m = 0; m < 4; ++m)
#pragma unroll
      for (int n = 0; n < 4; ++n)
        acc[m][n] = __builtin_amdgcn_mfma_f32_16x16x32_bf16(af[m], bf[n], acc[m][n], 0, 0, 0);
    __syncthreads();
  }

#pragma unroll
  for (int n = 0; n < 4; ++n) {
    const int col = bn + wc + n * 16 + li;
    const float bv = bias[col];
#pragma unroll
    for (int m = 0; m < 4; ++m) {
      const int row0 = bm + wr + m * 16 + g * 4;
#pragma unroll
      for (int r = 0; r < 4; ++r)
        store_out(C + (size_t)(row0 + r) * N + col, acc[m][n][r] + bv);
    }
  }
}

// ---------------- flash attention: KVBLK=128, 32 q-rows/wave, ones-col rowsum ----------------
// qkv: [4096][3072] bf16, q|k|v each [.,1024] with head h at cols h*64..h*64+63
// out: [4096][1024] bf16
// grid 512 (16 qt x 16 h x 2 b); block = 4 waves; each wave owns 2x16 q-rows.
__global__ __launch_bounds__(256, 2) void attn_kernel(
    const u16* __restrict__ qkv, u16* __restrict__ outp)
{
  __shared__ u16 Ks[2][128 * 64];   // [kv][d] dbuf (128B rows), 16B chunks XOR by (kv&7)
  __shared__ u16 Vt[64 * 128];      // [d][kv] (256B rows), byte XOR ((d^(d>>3))&7)<<4
  __shared__ u16 Pl[4 * 16 * 128];  // per-wave P[16q][128kv] (256B rows), XOR (q>>2)<<5

  const int tid = threadIdx.x;
  const int w = tid >> 6, l = tid & 63;
  const int g = l >> 4, li = l & 15;

  // T1: bijective XCD swizzle (512 = 8 * 64)
  const int lb = (blockIdx.x & 7) * 64 + (blockIdx.x >> 3);
  const int qt = lb & 15;
  const int h  = (lb >> 4) & 15;
  const int bb = lb >> 8;
  const size_t baserow = (size_t)bb * 2048;

  // hoisted Q fragments for both 16-row blocks (A: rows qt*128+w*16, B: +64)
  const int qbaseA = qt * 128 + w * 16;
  const u16* qpA = qkv + (baserow + qbaseA + li) * 3072 + h * 64 + 8 * g;
  const u16* qpB = qpA + (size_t)64 * 3072;
  const s16x8 qfA0 = *(const s16x8*)(qpA);
  const s16x8 qfA1 = *(const s16x8*)(qpA + 32);
  const s16x8 qfB0 = *(const s16x8*)(qpB);
  const s16x8 qfB1 = *(const s16x8*)(qpB + 32);

  // K staging: 1024 chunks/tile, 4 rounds; round j: chunk = j*256 + tid
  // chunk -> kv row (chunk>>3), slot (chunk&7); source col pre-swizzled by (row&7)
  const int kr = tid >> 3, kc = tid & 7;   // row base (0..31), +32j per round
  const u16* kg0 = qkv + (baserow + kr) * 3072 + 1024 + h * 64 + 8 * (kc ^ (kr & 7));

  // V reg-staging: thread owns kv-pairs {2vp,2vp+1} and {2vp+64,2vp+65} at d-group dg
  const int vp = tid >> 3, dg = tid & 7;
  const u16* vgA0 = qkv + (baserow + 2 * vp)      * 3072 + 2048 + h * 64 + 8 * dg;
  const u16* vgB0 = vgA0 + 3072;
  const u16* vgA1 = vgA0 + (size_t)64 * 3072;
  const u16* vgB1 = vgA1 + 3072;

  auto issueK = [&](int b, int t) {
    const size_t koff = (size_t)t * (128 * 3072);
#pragma unroll
    for (int j = 0; j < 4; ++j)
      gload16(kg0 + koff + (size_t)j * (32 * 3072), &Ks[b][j * 2048 + w * 512]);
  };

  // log2-domain online softmax state; rowsum via ones-column MFMA
  const float C1  = 0.18033688f;   // 0.125 * log2(e)
  const float THR = 11.5416f;      // 8 * log2(e)
  float MA[4], MB[4];
#pragma unroll
  for (int r = 0; r < 4; ++r) { MA[r] = -1e30f; MB[r] = -1e30f; }
  f32x4 oA[4] = {}, oB[4] = {}, osA = {}, osB = {};

  s16x8 ones;
#pragma unroll
  for (int j = 0; j < 8; ++j) ones[j] = (short)0x3F80;   // bf16 1.0

  char* Pw = (char*)(Pl + w * 2048);   // 4KB per wave

  // prologue: prefetch tile 0
  issueK(0, 0);
  s16x8 va0 = *(const s16x8*)vgA0;
  s16x8 vb0 = *(const s16x8*)vgB0;
  s16x8 va1 = *(const s16x8*)vgA1;
  s16x8 vb1 = *(const s16x8*)vgB1;

  int buf = 0;
  for (int t = 0; t < 16; ++t) {
    // V regs (tile t) -> Vt; paired-kv b32 writes, same XOR involution as reads
#pragma unroll
    for (int j = 0; j < 8; ++j) {
      const int d = 8 * dg + j;
      const int swz = ((d ^ (d >> 3)) & 7) << 4;
      const u32 val0 = (u32)(u16)va0[j] | ((u32)(u16)vb0[j] << 16);
      const u32 val1 = (u32)(u16)va1[j] | ((u32)(u16)vb1[j] << 16);
      *(u32*)((char*)Vt + d * 256 + ((4 * vp) ^ swz))       = val0;
      *(u32*)((char*)Vt + d * 256 + ((4 * vp + 128) ^ swz)) = val1;
    }
    __syncthreads();   // K[buf] gload drained; Vt visible

    if (t < 15) {      // prefetch next tile
      issueK(buf ^ 1, t + 1);
      const size_t koff = (size_t)(t + 1) * (128 * 3072);
      va0 = *(const s16x8*)(vgA0 + koff);
      vb0 = *(const s16x8*)(vgB0 + koff);
      va1 = *(const s16x8*)(vgA1 + koff);
      vb1 = *(const s16x8*)(vgB1 + koff);
    }

    const u16* kb = &Ks[buf][0];

    // ---- S = Q K^T for both q-blocks; 16 ds_read serve 32 MFMA ----
    f32x4 sA[8], sB[8];
#pragma unroll
    for (int nk = 0; nk < 8; ++nk) { sA[nk] = (f32x4){}; sB[nk] = (f32x4){}; }
    __builtin_amdgcn_s_setprio(1);
#pragma unroll
    for (int nk = 0; nk < 8; ++nk) {
      const int kvr = nk * 16 + li;
      const s16x8 kf0 = *(const s16x8*)((const char*)kb + kvr * 128 + 16 * ((0 + g) ^ (kvr & 7)));
      const s16x8 kf1 = *(const s16x8*)((const char*)kb + kvr * 128 + 16 * ((4 + g) ^ (kvr & 7)));
      sA[nk] = __builtin_amdgcn_mfma_f32_16x16x32_bf16(qfA0, kf0, sA[nk], 0, 0, 0);
      sA[nk] = __builtin_amdgcn_mfma_f32_16x16x32_bf16(qfA1, kf1, sA[nk], 0, 0, 0);
      sB[nk] = __builtin_amdgcn_mfma_f32_16x16x32_bf16(qfB0, kf0, sB[nk], 0, 0, 0);
      sB[nk] = __builtin_amdgcn_mfma_f32_16x16x32_bf16(qfB1, kf1, sB[nk], 0, 0, 0);
    }
    __builtin_amdgcn_s_setprio(0);

    // ---- defer-max (T13): lane-local check; rare full rescale ----
    float lmA[4], lmB[4];
    bool need = false;
#pragma unroll
    for (int r = 0; r < 4; ++r) {
      float mA = sA[0][r], mB = sB[0][r];
#pragma unroll
      for (int nk = 1; nk < 8; ++nk) {
        mA = fmaxf(mA, sA[nk][r]);
        mB = fmaxf(mB, sB[nk][r]);
      }
      lmA[r] = mA * C1;
      lmB[r] = mB * C1;
      need |= (lmA[r] > MA[r] + THR) | (lmB[r] > MB[r] + THR);
    }
    if (__any(need)) {
#pragma unroll
      for (int r = 0; r < 4; ++r) {
        float mxA = lmA[r], mxB = lmB[r];
#pragma unroll
        for (int off = 1; off < 16; off <<= 1) {
          mxA = fmaxf(mxA, __shfl_xor(mxA, off));
          mxB = fmaxf(mxB, __shfl_xor(mxB, off));
        }
        const float mnA = fmaxf(MA[r], mxA);
        const float mnB = fmaxf(MB[r], mxB);
        const float aA = exp2g(MA[r] - mnA);
        const float aB = exp2g(MB[r] - mnB);
        MA[r] = mnA; MB[r] = mnB;
        osA[r] *= aA; osB[r] *= aB;
#pragma unroll
        for (int nd = 0; nd < 4; ++nd) { oA[nd][r] *= aA; oB[nd][r] *= aB; }
      }
    }

    // ---- exp2 in place (P values, bounded by 2^THR) ----
#pragma unroll
    for (int r = 0; r < 4; ++r) {
#pragma unroll
      for (int nk = 0; nk < 8; ++nk) {
        sA[nk][r] = exp2g(fmaf(sA[nk][r], C1, -MA[r]));
        sB[nk][r] = exp2g(fmaf(sB[nk][r], C1, -MB[r]));
      }
    }

    // ---- block A: P -> LDS, PV + ones-column rowsum ----
#pragma unroll
    for (int nk = 0; nk < 8; ++nk)
#pragma unroll
      for (int r = 0; r < 4; ++r) {
        const int q = g * 4 + r;
        *(u16*)(Pw + q * 256 + ((nk * 32 + li * 2) ^ (g << 5))) = f2bf(sA[nk][r]);
      }
    asm volatile("s_waitcnt lgkmcnt(0)" ::: "memory");

    __builtin_amdgcn_s_setprio(1);
#pragma unroll
    for (int ks = 0; ks < 4; ++ks) {
      const s16x8 pf = *(const s16x8*)(Pw + li * 256 + ((ks * 64 + 16 * g) ^ (((li >> 2) & 3) << 5)));
#pragma unroll
      for (int nd = 0; nd < 4; ++nd) {
        const int d = nd * 16 + li;
        const s16x8 vf = *(const s16x8*)((char*)Vt + d * 256 + ((ks * 64 + 16 * g) ^ (((d ^ (d >> 3)) & 7) << 4)));
        oA[nd] = __builtin_amdgcn_mfma_f32_16x16x32_bf16(pf, vf, oA[nd], 0, 0, 0);
      }
      osA = __builtin_amdgcn_mfma_f32_16x16x32_bf16(pf, ones, osA, 0, 0, 0);
    }
    __builtin_amdgcn_s_setprio(0);
    asm volatile("s_waitcnt lgkmcnt(0)" ::: "memory");  // pf_A reads drained before overwrite

    // ---- block B: reuse the same P region ----
#pragma unroll
    for (int nk = 0; nk < 8; ++nk)
#pragma unroll
      for (int r = 0; r < 4; ++r) {
        const int q = g * 4 + r;
        *(u16*)(Pw + q * 256 + ((nk * 32 + li * 2) ^ (g << 5))) = f2bf(sB[nk][r]);
      }
    asm volatile("s_waitcnt lgkmcnt(0)" ::: "memory");

    __builtin_amdgcn_s_setprio(1);
#pragma unroll
    for (int ks = 0; ks < 4; ++ks) {
      const s16x8 pf = *(const s16x8*)(Pw + li * 256 + ((ks * 64 + 16 * g) ^ (((li >> 2) & 3) << 5)));
#pragma unroll
      for (int nd = 0; nd < 4; ++nd) {
        const int d = nd * 16 + li;
        const s16x8 vf = *(const s16x8*)((char*)Vt + d * 256 + ((ks * 64 + 16 * g) ^ (((d ^ (d >> 3)) & 7) << 4)));
        oB[nd] = __builtin_amdgcn_mfma_f32_16x16x32_bf16(pf, vf, oB[nd], 0, 0, 0);
      }
      osB = __builtin_amdgcn_mfma_f32_16x16x32_bf16(pf, ones, osB, 0, 0, 0);
    }
    __builtin_amdgcn_s_setprio(0);

    __syncthreads();   // all waves done with Ks[buf], Vt, prefetch drained
    buf ^= 1;
  }

  // ---- epilogue: normalize by ones-column rowsum, store bf16 ----
#pragma unroll
  for (int r = 0; r < 4; ++r) {
    const float invA = 1.0f / osA[r];
    const float invB = 1.0f / osB[r];
    const size_t rowA = baserow + qbaseA + g * 4 + r;
#pragma unroll
    for (int nd = 0; nd < 4; ++nd) {
      outp[rowA * 1024 + h * 64 + nd * 16 + li]        = f2bf(oA[nd][r] * invA);
      outp[(rowA + 64) * 1024 + h * 64 + nd * 16 + li] = f2bf(oB[nd][r] * invB);
    }
  }
}

// ---------------- launcher ----------------
extern "C" void kernel_launch(void* const* d_in, const int* in_sizes, int n_in,
                              void* d_out, int out_size, void* d_ws, size_t ws_size,
                              hipStream_t stream)
{
  const float* x     = (const float*)d_in[0];
  const float* gamma = (const float*)d_in[1];
  const float* beta  = (const float*)d_in[2];
  const float* Wqkv  = (const float*)d_in[3];
  const float* bqkv  = (const float*)d_in[4];
  const float* Wout  = (const float*)d_in[5];
  const float* bout  = (const float*)d_in[6];
  float* out = (float*)d_out;

  char* ws = (char*)d_ws;
  u16* xn     = (u16*)(ws);                       // 8 MB  [4096][1024]
  u16* wqkv_t = (u16*)(ws + ((size_t)8  << 20));  // 6 MB  [3072][1024]
  u16* wout_t = (u16*)(ws + ((size_t)14 << 20));  // 2 MB  [1024][1024]
  u16* qkv    = (u16*)(ws + ((size_t)16 << 20));  // 24 MB [4096][3072]
  u16* attn   = (u16*)(ws + ((size_t)40 << 20));  // 8 MB  [4096][1024]

  ln_kernel<<<4096, 256, 0, stream>>>(x, gamma, beta, xn);
  transpose_cvt<<<dim3(96, 32), dim3(32, 8), 0, stream>>>(Wqkv, wqkv_t, 1024, 3072);
  transpose_cvt<<<dim3(32, 32), dim3(32, 8), 0, stream>>>(Wout, wout_t, 1024, 1024);
  gemm_bt<u16><<<dim3(24, 32), 256, 0, stream>>>(xn, wqkv_t, bqkv, qkv, 4096, 3072, 1024);
  attn_kernel<<<512, 256, 0, stream>>>(qkv, attn);
  gemm_bt<float><<<dim3(8, 32), 256, 0, stream>>>(attn, wout_t, bout, out, 4096, 1024, 1024);
}

// Round 11
// 165.078 us; speedup vs baseline: 1.3371x; 1.0076x over previous
//
#include <hip/hip_runtime.h>

typedef unsigned short u16;
typedef unsigned int   u32;
typedef __attribute__((ext_vector_type(4)))  float  f32x4;
typedef __attribute__((ext_vector_type(8)))  short  s16x8;

__device__ __forceinline__ u16 f2bf(float f) {
  unsigned u = __builtin_bit_cast(unsigned, f);
  u += 0x7FFFu + ((u >> 16) & 1u);
  return (u16)(u >> 16);
}

__device__ __forceinline__ float exp2g(float x) { return __builtin_amdgcn_exp2f(x); }

__device__ __forceinline__ void gload16(const void* g, void* l) {
  __builtin_amdgcn_global_load_lds(
      (const __attribute__((address_space(1))) void*)g,
      (__attribute__((address_space(3))) void*)l, 16, 0, 0);
}

// ---------------- LayerNorm (fp32 in -> bf16 out) ----------------
__global__ __launch_bounds__(256) void ln_kernel(
    const float* __restrict__ x, const float* __restrict__ gamma,
    const float* __restrict__ beta, u16* __restrict__ xn)
{
  const int row = blockIdx.x, tid = threadIdx.x;
  const float* xr = x + (size_t)row * 1024;
  float4 v = *(const float4*)(xr + tid * 4);
  float s  = v.x + v.y + v.z + v.w;
  float s2 = v.x*v.x + v.y*v.y + v.z*v.z + v.w*v.w;
#pragma unroll
  for (int off = 32; off >= 1; off >>= 1) {
    s  += __shfl_xor(s,  off);
    s2 += __shfl_xor(s2, off);
  }
  __shared__ float red[8];
  const int w = tid >> 6, l = tid & 63;
  if (l == 0) { red[w] = s; red[w + 4] = s2; }
  __syncthreads();
  s  = red[0] + red[1] + red[2] + red[3];
  s2 = red[4] + red[5] + red[6] + red[7];
  const float mu  = s * (1.0f / 1024.0f);
  const float var = s2 * (1.0f / 1024.0f) - mu * mu;
  const float rs  = rsqrtf(var + 1e-5f);
  float4 g  = *(const float4*)(gamma + tid * 4);
  float4 be = *(const float4*)(beta  + tid * 4);
  ushort4 o;
  o.x = f2bf((v.x - mu) * rs * g.x + be.x);
  o.y = f2bf((v.y - mu) * rs * g.y + be.y);
  o.z = f2bf((v.z - mu) * rs * g.z + be.z);
  o.w = f2bf((v.w - mu) * rs * g.w + be.w);
  *(ushort4*)(xn + (size_t)row * 1024 + tid * 4) = o;
}

// ---------------- transpose + fp32->bf16 convert ----------------
__global__ void transpose_cvt(const float* __restrict__ in, u16* __restrict__ out,
                              int R, int C)
{
  __shared__ float t[32][33];
  const int bc = blockIdx.x * 32, br = blockIdx.y * 32;
  const int x = threadIdx.x;
#pragma unroll
  for (int i = threadIdx.y; i < 32; i += 8)
    t[i][x] = in[(size_t)(br + i) * C + bc + x];
  __syncthreads();
#pragma unroll
  for (int i = threadIdx.y; i < 32; i += 8)
    out[(size_t)(bc + i) * R + br + x] = f2bf(t[x][i]);
}

// ---------------- GEMM: C[M][N] = A[M][K] * Bt[N][K]^T + bias ----------------
__device__ __forceinline__ void store_out(float* p, float v) { *p = v; }
__device__ __forceinline__ void store_out(u16* p, float v)   { *p = f2bf(v); }

template <typename OutT>
__global__ __launch_bounds__(256) void gemm_bt(
    const u16* __restrict__ A, const u16* __restrict__ Bt,
    const float* __restrict__ bias, OutT* __restrict__ C,
    int M, int N, int K)
{
  __shared__ u16 As[128 * 32];
  __shared__ u16 Bs[128 * 32];
  const int tid = threadIdx.x;
  const int w = tid >> 6, l = tid & 63;
  const int g = l >> 4, li = l & 15;
  const int bm = blockIdx.y * 128, bn = blockIdx.x * 128;
  const int wr = (w >> 1) * 64, wc = (w & 1) * 64;

  f32x4 acc[4][4] = {};

  const int ar0 = tid >> 2,          as0 = tid & 3;
  const int ar1 = (tid + 256) >> 2,  as1 = (tid + 256) & 3;
  const u16* pa0 = A  + (size_t)(bm + ar0) * K + 8 * (as0 ^ (ar0 & 3));
  const u16* pa1 = A  + (size_t)(bm + ar1) * K + 8 * (as1 ^ (ar1 & 3));
  const u16* pb0 = Bt + (size_t)(bn + ar0) * K + 8 * (as0 ^ (ar0 & 3));
  const u16* pb1 = Bt + (size_t)(bn + ar1) * K + 8 * (as1 ^ (ar1 & 3));
  u16* la0 = As + w * 512;
  u16* la1 = As + 2048 + w * 512;
  u16* lb0 = Bs + w * 512;
  u16* lb1 = Bs + 2048 + w * 512;

  for (int kt = 0; kt < K; kt += 32) {
    gload16(pa0 + kt, la0);
    gload16(pa1 + kt, la1);
    gload16(pb0 + kt, lb0);
    gload16(pb1 + kt, lb1);
    __syncthreads();

    s16x8 af[4], bf[4];
#pragma unroll
    for (int m = 0; m < 4; ++m) {
      const int row = wr + m * 16 + li;
      af[m] = *(const s16x8*)(As + row * 32 + 8 * (g ^ (row & 3)));
    }
#pragma unroll
    for (int n = 0; n < 4; ++n) {
      const int row = wc + n * 16 + li;
      bf[n] = *(const s16x8*)(Bs + row * 32 + 8 * (g ^ (row & 3)));
    }
#pragma unroll
    for (int m = 0; m < 4; ++m)
#pragma unroll
      for (int n = 0; n < 4; ++n)
        acc[m][n] = __builtin_amdgcn_mfma_f32_16x16x32_bf16(af[m], bf[n], acc[m][n], 0, 0, 0);
    __syncthreads();
  }

#pragma unroll
  for (int n = 0; n < 4; ++n) {
    const int col = bn + wc + n * 16 + li;
    const float bv = bias[col];
#pragma unroll
    for (int m = 0; m < 4; ++m) {
      const int row0 = bm + wr + m * 16 + g * 4;
#pragma unroll
      for (int r = 0; r < 4; ++r)
        store_out(C + (size_t)(row0 + r) * N + col, acc[m][n][r] + bv);
    }
  }
}

// ---------------- flash attention: 16 q-rows/wave, grid 1024, 4 blk/CU ----------------
// qkv: [4096][3072] bf16, q|k|v each [.,1024] with head h at cols h*64..h*64+63
// out: [4096][1024] bf16
// grid 1024 (32 qt x 16 h x 2 b); block = 4 waves; each wave owns 16 q-rows.
__global__ __launch_bounds__(256, 4) void attn_kernel(
    const u16* __restrict__ qkv, u16* __restrict__ outp)
{
  __shared__ u16 Ks[2][4096];   // [kv][d] dbuf, 16B chunks XOR-swizzled by (kv&7)  (verified)
  __shared__ u16 Vt[4096];      // [d][kv] single, byte XOR ((d^(d>>3))&7)<<4       (verified)
  __shared__ u16 Pl[4 * 1024];  // per-wave P[16q][64kv], swizzled by (g<<5)        (verified)

  const int tid = threadIdx.x;
  const int w = tid >> 6, l = tid & 63;
  const int g = l >> 4, li = l & 15;

  // T1: bijective XCD swizzle (1024 = 8 * 128)
  const int lb = (blockIdx.x & 7) * 128 + (blockIdx.x >> 3);
  const int qt = lb & 31;
  const int h  = (lb >> 5) & 15;
  const int bb = lb >> 9;
  const size_t baserow = (size_t)bb * 2048;

  // hoisted Q fragments: 16 rows per wave (rows qt*64 + w*16 ..)
  const int qbase = qt * 64 + w * 16;
  const u16* qp = qkv + (baserow + qbase + li) * 3072 + h * 64 + 8 * g;
  const s16x8 qf0 = *(const s16x8*)(qp);
  const s16x8 qf1 = *(const s16x8*)(qp + 32);

  // K staging (verified): chunk c -> kv c>>3, slot c&7, pre-swizzled source
  const int kr0 = tid >> 3,         kc0 = tid & 7;
  const int kr1 = (tid + 256) >> 3, kc1 = (tid + 256) & 7;
  const u16* kg0 = qkv + (baserow + kr0) * 3072 + 1024 + h * 64 + 8 * (kc0 ^ (kr0 & 7));
  const u16* kg1 = qkv + (baserow + kr1) * 3072 + 1024 + h * 64 + 8 * (kc1 ^ (kr1 & 7));

  // V reg-staging: thread owns kv-pair vp x d-group dg
  const int vp = tid >> 3, dg = tid & 7;
  const u16* vgA = qkv + (baserow + 2 * vp)     * 3072 + 2048 + h * 64 + 8 * dg;
  const u16* vgB = qkv + (baserow + 2 * vp + 1) * 3072 + 2048 + h * 64 + 8 * dg;

  auto issueK = [&](int b, int t) {
    const size_t koff = (size_t)t * (64 * 3072);
    gload16(kg0 + koff, &Ks[b][w * 512]);
    gload16(kg1 + koff, &Ks[b][2048 + w * 512]);
  };

  // log2-domain online softmax state; rowsum via ones-column MFMA
  const float C1  = 0.18033688f;   // 0.125 * log2(e)
  const float THR = 11.5416f;      // 8 * log2(e)
  float M[4];
#pragma unroll
  for (int r = 0; r < 4; ++r) M[r] = -1e30f;
  f32x4 o[4] = {}, os = {};

  s16x8 ones;
#pragma unroll
  for (int j = 0; j < 8; ++j) ones[j] = (short)0x3F80;   // bf16 1.0

  char* Pw = (char*)(Pl + w * 1024);

  // prologue: prefetch tile 0
  issueK(0, 0);
  s16x8 va = *(const s16x8*)vgA;
  s16x8 vb = *(const s16x8*)vgB;

  int buf = 0;
  for (int t = 0; t < 32; ++t) {
    // V regs (tile t) -> Vt; paired-kv b32 writes, verified swizzle involution
#pragma unroll
    for (int j = 0; j < 8; ++j) {
      const int d = 8 * dg + j;
      const u32 val = (u32)(u16)va[j] | ((u32)(u16)vb[j] << 16);
      *(u32*)((char*)Vt + d * 128 + ((4 * vp) ^ ((((d ^ (d >> 3)) & 7)) << 4))) = val;
    }
    __syncthreads();   // K[buf] gload drained; Vt visible

    if (t < 31) {      // prefetch next tile
      issueK(buf ^ 1, t + 1);
      const size_t koff = (size_t)(t + 1) * (64 * 3072);
      va = *(const s16x8*)(vgA + koff);
      vb = *(const s16x8*)(vgB + koff);
    }

    const u16* kb = &Ks[buf][0];

    // ---- S = Q K^T ----
    f32x4 s[4] = {};
    __builtin_amdgcn_s_setprio(1);
#pragma unroll
    for (int nk = 0; nk < 4; ++nk) {
      const int kvr = nk * 16 + li;
      const s16x8 kf0 = *(const s16x8*)((const char*)kb + kvr * 128 + 16 * ((0 + g) ^ (kvr & 7)));
      const s16x8 kf1 = *(const s16x8*)((const char*)kb + kvr * 128 + 16 * ((4 + g) ^ (kvr & 7)));
      s[nk] = __builtin_amdgcn_mfma_f32_16x16x32_bf16(qf0, kf0, s[nk], 0, 0, 0);
      s[nk] = __builtin_amdgcn_mfma_f32_16x16x32_bf16(qf1, kf1, s[nk], 0, 0, 0);
    }
    __builtin_amdgcn_s_setprio(0);

    // ---- defer-max (T13): lane-local check; rare full rescale ----
    float lm[4];
    bool need = false;
#pragma unroll
    for (int r = 0; r < 4; ++r) {
      lm[r] = fmaxf(fmaxf(s[0][r], s[1][r]), fmaxf(s[2][r], s[3][r])) * C1;
      need |= (lm[r] > M[r] + THR);
    }
    if (__any(need)) {
#pragma unroll
      for (int r = 0; r < 4; ++r) {
        float mx = lm[r];
#pragma unroll
        for (int off = 1; off < 16; off <<= 1) mx = fmaxf(mx, __shfl_xor(mx, off));
        const float mn = fmaxf(M[r], mx);
        const float a = exp2g(M[r] - mn);
        M[r] = mn;
        os[r] *= a;
#pragma unroll
        for (int nd = 0; nd < 4; ++nd) o[nd][r] *= a;
      }
    }

    // ---- exp2 in place (P values, bounded by 2^THR) ----
#pragma unroll
    for (int r = 0; r < 4; ++r)
#pragma unroll
      for (int nk = 0; nk < 4; ++nk)
        s[nk][r] = exp2g(fmaf(s[nk][r], C1, -M[r]));

    // ---- P -> LDS, PV + ones-column rowsum ----
#pragma unroll
    for (int nk = 0; nk < 4; ++nk)
#pragma unroll
      for (int r = 0; r < 4; ++r) {
        const int q = g * 4 + r;
        *(u16*)(Pw + q * 128 + ((nk * 32 + li * 2) ^ (g << 5))) = f2bf(s[nk][r]);
      }
    asm volatile("s_waitcnt lgkmcnt(0)" ::: "memory");

    __builtin_amdgcn_s_setprio(1);
#pragma unroll
    for (int ks = 0; ks < 2; ++ks) {
      const s16x8 pf = *(const s16x8*)(Pw + li * 128 + ((ks * 64 + 16 * g) ^ (((li >> 2) & 3) << 5)));
#pragma unroll
      for (int nd = 0; nd < 4; ++nd) {
        const int d = nd * 16 + li;
        const s16x8 vf = *(const s16x8*)((char*)Vt + d * 128 + ((ks * 64 + 16 * g) ^ (((d ^ (d >> 3)) & 7) << 4)));
        o[nd] = __builtin_amdgcn_mfma_f32_16x16x32_bf16(pf, vf, o[nd], 0, 0, 0);
      }
      os = __builtin_amdgcn_mfma_f32_16x16x32_bf16(pf, ones, os, 0, 0, 0);
    }
    __builtin_amdgcn_s_setprio(0);

    __syncthreads();   // all waves done with Ks[buf], Vt; prefetch drained
    buf ^= 1;
  }

  // ---- epilogue: normalize by ones-column rowsum, store bf16 ----
#pragma unroll
  for (int r = 0; r < 4; ++r) {
    const float inv = 1.0f / os[r];
    const size_t row = baserow + qbase + g * 4 + r;
#pragma unroll
    for (int nd = 0; nd < 4; ++nd)
      outp[row * 1024 + h * 64 + nd * 16 + li] = f2bf(o[nd][r] * inv);
  }
}

// ---------------- launcher ----------------
extern "C" void kernel_launch(void* const* d_in, const int* in_sizes, int n_in,
                              void* d_out, int out_size, void* d_ws, size_t ws_size,
                              hipStream_t stream)
{
  const float* x     = (const float*)d_in[0];
  const float* gamma = (const float*)d_in[1];
  const float* beta  = (const float*)d_in[2];
  const float* Wqkv  = (const float*)d_in[3];
  const float* bqkv  = (const float*)d_in[4];
  const float* Wout  = (const float*)d_in[5];
  const float* bout  = (const float*)d_in[6];
  float* out = (float*)d_out;

  char* ws = (char*)d_ws;
  u16* xn     = (u16*)(ws);                       // 8 MB  [4096][1024]
  u16* wqkv_t = (u16*)(ws + ((size_t)8  << 20));  // 6 MB  [3072][1024]
  u16* wout_t = (u16*)(ws + ((size_t)14 << 20));  // 2 MB  [1024][1024]
  u16* qkv    = (u16*)(ws + ((size_t)16 << 20));  // 24 MB [4096][3072]
  u16* attn   = (u16*)(ws + ((size_t)40 << 20));  // 8 MB  [4096][1024]

  ln_kernel<<<4096, 256, 0, stream>>>(x, gamma, beta, xn);
  transpose_cvt<<<dim3(96, 32), dim3(32, 8), 0, stream>>>(Wqkv, wqkv_t, 1024, 3072);
  transpose_cvt<<<dim3(32, 32), dim3(32, 8), 0, stream>>>(Wout, wout_t, 1024, 1024);
  gemm_bt<u16><<<dim3(24, 32), 256, 0, stream>>>(xn, wqkv_t, bqkv, qkv, 4096, 3072, 1024);
  attn_kernel<<<1024, 256, 0, stream>>>(qkv, attn);
  gemm_bt<float><<<dim3(8, 32), 256, 0, stream>>>(attn, wout_t, bout, out, 4096, 1024, 1024);
}

// Round 12
// 143.643 us; speedup vs baseline: 1.5366x; 1.1492x over previous
//
#include <hip/hip_runtime.h>

typedef unsigned short u16;
typedef unsigned int   u32;
typedef __attribute__((ext_vector_type(4)))  float  f32x4;
typedef __attribute__((ext_vector_type(8)))  short  s16x8;

__device__ __forceinline__ u16 f2bf(float f) {
  unsigned u = __builtin_bit_cast(unsigned, f);
  u += 0x7FFFu + ((u >> 16) & 1u);
  return (u16)(u >> 16);
}

__device__ __forceinline__ float exp2g(float x) { return __builtin_amdgcn_exp2f(x); }

__device__ __forceinline__ void gload16(const void* g, void* l) {
  __builtin_amdgcn_global_load_lds(
      (const __attribute__((address_space(1))) void*)g,
      (__attribute__((address_space(3))) void*)l, 16, 0, 0);
}

// ---------------- LayerNorm (fp32 in -> bf16 out) ----------------
__global__ __launch_bounds__(256) void ln_kernel(
    const float* __restrict__ x, const float* __restrict__ gamma,
    const float* __restrict__ beta, u16* __restrict__ xn)
{
  const int row = blockIdx.x, tid = threadIdx.x;
  const float* xr = x + (size_t)row * 1024;
  float4 v = *(const float4*)(xr + tid * 4);
  float s  = v.x + v.y + v.z + v.w;
  float s2 = v.x*v.x + v.y*v.y + v.z*v.z + v.w*v.w;
#pragma unroll
  for (int off = 32; off >= 1; off >>= 1) {
    s  += __shfl_xor(s,  off);
    s2 += __shfl_xor(s2, off);
  }
  __shared__ float red[8];
  const int w = tid >> 6, l = tid & 63;
  if (l == 0) { red[w] = s; red[w + 4] = s2; }
  __syncthreads();
  s  = red[0] + red[1] + red[2] + red[3];
  s2 = red[4] + red[5] + red[6] + red[7];
  const float mu  = s * (1.0f / 1024.0f);
  const float var = s2 * (1.0f / 1024.0f) - mu * mu;
  const float rs  = rsqrtf(var + 1e-5f);
  float4 g  = *(const float4*)(gamma + tid * 4);
  float4 be = *(const float4*)(beta  + tid * 4);
  ushort4 o;
  o.x = f2bf((v.x - mu) * rs * g.x + be.x);
  o.y = f2bf((v.y - mu) * rs * g.y + be.y);
  o.z = f2bf((v.z - mu) * rs * g.z + be.z);
  o.w = f2bf((v.w - mu) * rs * g.w + be.w);
  *(ushort4*)(xn + (size_t)row * 1024 + tid * 4) = o;
}

// ---------------- transpose + fp32->bf16 convert ----------------
__global__ void transpose_cvt(const float* __restrict__ in, u16* __restrict__ out,
                              int R, int C)
{
  __shared__ float t[32][33];
  const int bc = blockIdx.x * 32, br = blockIdx.y * 32;
  const int x = threadIdx.x;
#pragma unroll
  for (int i = threadIdx.y; i < 32; i += 8)
    t[i][x] = in[(size_t)(br + i) * C + bc + x];
  __syncthreads();
#pragma unroll
  for (int i = threadIdx.y; i < 32; i += 8)
    out[(size_t)(bc + i) * R + br + x] = f2bf(t[x][i]);
}

// ---------------- GEMM (2-phase dbuf): C[M][N] = A[M][K] * Bt[N][K]^T + bias ----------------
__device__ __forceinline__ void store_out(float* p, float v) { *p = v; }
__device__ __forceinline__ void store_out(u16* p, float v)   { *p = f2bf(v); }

template <typename OutT>
__global__ __launch_bounds__(256) void gemm_bt(
    const u16* __restrict__ A, const u16* __restrict__ Bt,
    const float* __restrict__ bias, OutT* __restrict__ C,
    int M, int N, int K)
{
  __shared__ u16 As[2][128 * 32];
  __shared__ u16 Bs[2][128 * 32];
  const int tid = threadIdx.x;
  const int w = tid >> 6, l = tid & 63;
  const int g = l >> 4, li = l & 15;
  const int bm = blockIdx.y * 128, bn = blockIdx.x * 128;
  const int wr = (w >> 1) * 64, wc = (w & 1) * 64;

  f32x4 acc[4][4] = {};

  // staging: 512 16B chunks per tile; thread handles chunks tid and tid+256.
  // chunk c -> row c>>2, slot c&3 ; slot s holds global k-chunk (s ^ (row&3))
  const int ar0 = tid >> 2,          as0 = tid & 3;
  const int ar1 = (tid + 256) >> 2,  as1 = (tid + 256) & 3;
  const u16* pa0 = A  + (size_t)(bm + ar0) * K + 8 * (as0 ^ (ar0 & 3));
  const u16* pa1 = A  + (size_t)(bm + ar1) * K + 8 * (as1 ^ (ar1 & 3));
  const u16* pb0 = Bt + (size_t)(bn + ar0) * K + 8 * (as0 ^ (ar0 & 3));
  const u16* pb1 = Bt + (size_t)(bn + ar1) * K + 8 * (as1 ^ (ar1 & 3));

  auto stage = [&](int b, int kt) {
    gload16(pa0 + kt, &As[b][w * 512]);
    gload16(pa1 + kt, &As[b][2048 + w * 512]);
    gload16(pb0 + kt, &Bs[b][w * 512]);
    gload16(pb1 + kt, &Bs[b][2048 + w * 512]);
  };

  // prologue: stage tile 0
  stage(0, 0);

  int buf = 0;
  for (int kt = 0; kt < K; kt += 32) {
    __syncthreads();                 // stage(buf) drained (vmcnt) + buf safe to read;
                                     // also: all waves done reading buf from 2 iters ago
    if (kt + 32 < K) stage(buf ^ 1, kt + 32);   // overlap next stage with compute

    const u16* as = &As[buf][0];
    const u16* bs = &Bs[buf][0];

    s16x8 af[4], bf[4];
#pragma unroll
    for (int m = 0; m < 4; ++m) {
      const int row = wr + m * 16 + li;
      af[m] = *(const s16x8*)(as + row * 32 + 8 * (g ^ (row & 3)));
    }
#pragma unroll
    for (int n = 0; n < 4; ++n) {
      const int row = wc + n * 16 + li;
      bf[n] = *(const s16x8*)(bs + row * 32 + 8 * (g ^ (row & 3)));
    }
    __builtin_amdgcn_s_setprio(1);
#pragma unroll
    for (int m = 0; m < 4; ++m)
#pragma unroll
      for (int n = 0; n < 4; ++n)
        acc[m][n] = __builtin_amdgcn_mfma_f32_16x16x32_bf16(af[m], bf[n], acc[m][n], 0, 0, 0);
    __builtin_amdgcn_s_setprio(0);

    buf ^= 1;
  }

#pragma unroll
  for (int n = 0; n < 4; ++n) {
    const int col = bn + wc + n * 16 + li;
    const float bv = bias[col];
#pragma unroll
    for (int m = 0; m < 4; ++m) {
      const int row0 = bm + wr + m * 16 + g * 4;
#pragma unroll
      for (int r = 0; r < 4; ++r)
        store_out(C + (size_t)(row0 + r) * N + col, acc[m][n][r] + bv);
    }
  }
}

// ---------------- flash attention: 16 q-rows/wave, grid 1024, 4 blk/CU ----------------
// (unchanged from r11: 83 µs, verified)
__global__ __launch_bounds__(256, 4) void attn_kernel(
    const u16* __restrict__ qkv, u16* __restrict__ outp)
{
  __shared__ u16 Ks[2][4096];   // [kv][d] dbuf, 16B chunks XOR-swizzled by (kv&7)  (verified)
  __shared__ u16 Vt[4096];      // [d][kv] single, byte XOR ((d^(d>>3))&7)<<4       (verified)
  __shared__ u16 Pl[4 * 1024];  // per-wave P[16q][64kv], swizzled by (g<<5)        (verified)

  const int tid = threadIdx.x;
  const int w = tid >> 6, l = tid & 63;
  const int g = l >> 4, li = l & 15;

  // T1: bijective XCD swizzle (1024 = 8 * 128)
  const int lb = (blockIdx.x & 7) * 128 + (blockIdx.x >> 3);
  const int qt = lb & 31;
  const int h  = (lb >> 5) & 15;
  const int bb = lb >> 9;
  const size_t baserow = (size_t)bb * 2048;

  // hoisted Q fragments: 16 rows per wave (rows qt*64 + w*16 ..)
  const int qbase = qt * 64 + w * 16;
  const u16* qp = qkv + (baserow + qbase + li) * 3072 + h * 64 + 8 * g;
  const s16x8 qf0 = *(const s16x8*)(qp);
  const s16x8 qf1 = *(const s16x8*)(qp + 32);

  // K staging (verified): chunk c -> kv c>>3, slot c&7, pre-swizzled source
  const int kr0 = tid >> 3,         kc0 = tid & 7;
  const int kr1 = (tid + 256) >> 3, kc1 = (tid + 256) & 7;
  const u16* kg0 = qkv + (baserow + kr0) * 3072 + 1024 + h * 64 + 8 * (kc0 ^ (kr0 & 7));
  const u16* kg1 = qkv + (baserow + kr1) * 3072 + 1024 + h * 64 + 8 * (kc1 ^ (kr1 & 7));

  // V reg-staging: thread owns kv-pair vp x d-group dg
  const int vp = tid >> 3, dg = tid & 7;
  const u16* vgA = qkv + (baserow + 2 * vp)     * 3072 + 2048 + h * 64 + 8 * dg;
  const u16* vgB = qkv + (baserow + 2 * vp + 1) * 3072 + 2048 + h * 64 + 8 * dg;

  auto issueK = [&](int b, int t) {
    const size_t koff = (size_t)t * (64 * 3072);
    gload16(kg0 + koff, &Ks[b][w * 512]);
    gload16(kg1 + koff, &Ks[b][2048 + w * 512]);
  };

  // log2-domain online softmax state; rowsum via ones-column MFMA
  const float C1  = 0.18033688f;   // 0.125 * log2(e)
  const float THR = 11.5416f;      // 8 * log2(e)
  float M[4];
#pragma unroll
  for (int r = 0; r < 4; ++r) M[r] = -1e30f;
  f32x4 o[4] = {}, os = {};

  s16x8 ones;
#pragma unroll
  for (int j = 0; j < 8; ++j) ones[j] = (short)0x3F80;   // bf16 1.0

  char* Pw = (char*)(Pl + w * 1024);

  // prologue: prefetch tile 0
  issueK(0, 0);
  s16x8 va = *(const s16x8*)vgA;
  s16x8 vb = *(const s16x8*)vgB;

  int buf = 0;
  for (int t = 0; t < 32; ++t) {
    // V regs (tile t) -> Vt; paired-kv b32 writes, verified swizzle involution
#pragma unroll
    for (int j = 0; j < 8; ++j) {
      const int d = 8 * dg + j;
      const u32 val = (u32)(u16)va[j] | ((u32)(u16)vb[j] << 16);
      *(u32*)((char*)Vt + d * 128 + ((4 * vp) ^ ((((d ^ (d >> 3)) & 7)) << 4))) = val;
    }
    __syncthreads();   // K[buf] gload drained; Vt visible

    if (t < 31) {      // prefetch next tile
      issueK(buf ^ 1, t + 1);
      const size_t koff = (size_t)(t + 1) * (64 * 3072);
      va = *(const s16x8*)(vgA + koff);
      vb = *(const s16x8*)(vgB + koff);
    }

    const u16* kb = &Ks[buf][0];

    // ---- S = Q K^T ----
    f32x4 s[4] = {};
    __builtin_amdgcn_s_setprio(1);
#pragma unroll
    for (int nk = 0; nk < 4; ++nk) {
      const int kvr = nk * 16 + li;
      const s16x8 kf0 = *(const s16x8*)((const char*)kb + kvr * 128 + 16 * ((0 + g) ^ (kvr & 7)));
      const s16x8 kf1 = *(const s16x8*)((const char*)kb + kvr * 128 + 16 * ((4 + g) ^ (kvr & 7)));
      s[nk] = __builtin_amdgcn_mfma_f32_16x16x32_bf16(qf0, kf0, s[nk], 0, 0, 0);
      s[nk] = __builtin_amdgcn_mfma_f32_16x16x32_bf16(qf1, kf1, s[nk], 0, 0, 0);
    }
    __builtin_amdgcn_s_setprio(0);

    // ---- defer-max (T13): lane-local check; rare full rescale ----
    float lm[4];
    bool need = false;
#pragma unroll
    for (int r = 0; r < 4; ++r) {
      lm[r] = fmaxf(fmaxf(s[0][r], s[1][r]), fmaxf(s[2][r], s[3][r])) * C1;
      need |= (lm[r] > M[r] + THR);
    }
    if (__any(need)) {
#pragma unroll
      for (int r = 0; r < 4; ++r) {
        float mx = lm[r];
#pragma unroll
        for (int off = 1; off < 16; off <<= 1) mx = fmaxf(mx, __shfl_xor(mx, off));
        const float mn = fmaxf(M[r], mx);
        const float a = exp2g(M[r] - mn);
        M[r] = mn;
        os[r] *= a;
#pragma unroll
        for (int nd = 0; nd < 4; ++nd) o[nd][r] *= a;
      }
    }

    // ---- exp2 in place (P values, bounded by 2^THR) ----
#pragma unroll
    for (int r = 0; r < 4; ++r)
#pragma unroll
      for (int nk = 0; nk < 4; ++nk)
        s[nk][r] = exp2g(fmaf(s[nk][r], C1, -M[r]));

    // ---- P -> LDS, PV + ones-column rowsum ----
#pragma unroll
    for (int nk = 0; nk < 4; ++nk)
#pragma unroll
      for (int r = 0; r < 4; ++r) {
        const int q = g * 4 + r;
        *(u16*)(Pw + q * 128 + ((nk * 32 + li * 2) ^ (g << 5))) = f2bf(s[nk][r]);
      }
    asm volatile("s_waitcnt lgkmcnt(0)" ::: "memory");

    __builtin_amdgcn_s_setprio(1);
#pragma unroll
    for (int ks = 0; ks < 2; ++ks) {
      const s16x8 pf = *(const s16x8*)(Pw + li * 128 + ((ks * 64 + 16 * g) ^ (((li >> 2) & 3) << 5)));
#pragma unroll
      for (int nd = 0; nd < 4; ++nd) {
        const int d = nd * 16 + li;
        const s16x8 vf = *(const s16x8*)((char*)Vt + d * 128 + ((ks * 64 + 16 * g) ^ (((d ^ (d >> 3)) & 7) << 4)));
        o[nd] = __builtin_amdgcn_mfma_f32_16x16x32_bf16(pf, vf, o[nd], 0, 0, 0);
      }
      os = __builtin_amdgcn_mfma_f32_16x16x32_bf16(pf, ones, os, 0, 0, 0);
    }
    __builtin_amdgcn_s_setprio(0);

    __syncthreads();   // all waves done with Ks[buf], Vt; prefetch drained
    buf ^= 1;
  }

  // ---- epilogue: normalize by ones-column rowsum, store bf16 ----
#pragma unroll
  for (int r = 0; r < 4; ++r) {
    const float inv = 1.0f / os[r];
    const size_t row = baserow + qbase + g * 4 + r;
#pragma unroll
    for (int nd = 0; nd < 4; ++nd)
      outp[row * 1024 + h * 64 + nd * 16 + li] = f2bf(o[nd][r] * inv);
  }
}

// ---------------- launcher ----------------
extern "C" void kernel_launch(void* const* d_in, const int* in_sizes, int n_in,
                              void* d_out, int out_size, void* d_ws, size_t ws_size,
                              hipStream_t stream)
{
  const float* x     = (const float*)d_in[0];
  const float* gamma = (const float*)d_in[1];
  const float* beta  = (const float*)d_in[2];
  const float* Wqkv  = (const float*)d_in[3];
  const float* bqkv  = (const float*)d_in[4];
  const float* Wout  = (const float*)d_in[5];
  const float* bout  = (const float*)d_in[6];
  float* out = (float*)d_out;

  char* ws = (char*)d_ws;
  u16* xn     = (u16*)(ws);                       // 8 MB  [4096][1024]
  u16* wqkv_t = (u16*)(ws + ((size_t)8  << 20));  // 6 MB  [3072][1024]
  u16* wout_t = (u16*)(ws + ((size_t)14 << 20));  // 2 MB  [1024][1024]
  u16* qkv    = (u16*)(ws + ((size_t)16 << 20));  // 24 MB [4096][3072]
  u16* attn   = (u16*)(ws + ((size_t)40 << 20));  // 8 MB  [4096][1024]

  ln_kernel<<<4096, 256, 0, stream>>>(x, gamma, beta, xn);
  transpose_cvt<<<dim3(96, 32), dim3(32, 8), 0, stream>>>(Wqkv, wqkv_t, 1024, 3072);
  transpose_cvt<<<dim3(32, 32), dim3(32, 8), 0, stream>>>(Wout, wout_t, 1024, 1024);
  gemm_bt<u16><<<dim3(24, 32), 256, 0, stream>>>(xn, wqkv_t, bqkv, qkv, 4096, 3072, 1024);
  attn_kernel<<<1024, 256, 0, stream>>>(qkv, attn);
  gemm_bt<float><<<dim3(8, 32), 256, 0, stream>>>(attn, wout_t, bout, out, 4096, 1024, 1024);
}

// Round 13
// 135.721 us; speedup vs baseline: 1.6263x; 1.0584x over previous
//
#include <hip/hip_runtime.h>

typedef unsigned short u16;
typedef unsigned int   u32;
typedef __attribute__((ext_vector_type(2)))  unsigned u32x2;
typedef __attribute__((ext_vector_type(4)))  float  f32x4;
typedef __attribute__((ext_vector_type(8)))  short  s16x8;

__device__ __forceinline__ u16 f2bf(float f) {
  unsigned u = __builtin_bit_cast(unsigned, f);
  u += 0x7FFFu + ((u >> 16) & 1u);
  return (u16)(u >> 16);
}

__device__ __forceinline__ float exp2g(float x) { return __builtin_amdgcn_exp2f(x); }

__device__ __forceinline__ void gload16(const void* g, void* l) {
  __builtin_amdgcn_global_load_lds(
      (const __attribute__((address_space(1))) void*)g,
      (__attribute__((address_space(3))) void*)l, 16, 0, 0);
}

// ---------------- LayerNorm (fp32 in -> bf16 out) ----------------
__global__ __launch_bounds__(256) void ln_kernel(
    const float* __restrict__ x, const float* __restrict__ gamma,
    const float* __restrict__ beta, u16* __restrict__ xn)
{
  const int row = blockIdx.x, tid = threadIdx.x;
  const float* xr = x + (size_t)row * 1024;
  float4 v = *(const float4*)(xr + tid * 4);
  float s  = v.x + v.y + v.z + v.w;
  float s2 = v.x*v.x + v.y*v.y + v.z*v.z + v.w*v.w;
#pragma unroll
  for (int off = 32; off >= 1; off >>= 1) {
    s  += __shfl_xor(s,  off);
    s2 += __shfl_xor(s2, off);
  }
  __shared__ float red[8];
  const int w = tid >> 6, l = tid & 63;
  if (l == 0) { red[w] = s; red[w + 4] = s2; }
  __syncthreads();
  s  = red[0] + red[1] + red[2] + red[3];
  s2 = red[4] + red[5] + red[6] + red[7];
  const float mu  = s * (1.0f / 1024.0f);
  const float var = s2 * (1.0f / 1024.0f) - mu * mu;
  const float rs  = rsqrtf(var + 1e-5f);
  float4 g  = *(const float4*)(gamma + tid * 4);
  float4 be = *(const float4*)(beta  + tid * 4);
  ushort4 o;
  o.x = f2bf((v.x - mu) * rs * g.x + be.x);
  o.y = f2bf((v.y - mu) * rs * g.y + be.y);
  o.z = f2bf((v.z - mu) * rs * g.z + be.z);
  o.w = f2bf((v.w - mu) * rs * g.w + be.w);
  *(ushort4*)(xn + (size_t)row * 1024 + tid * 4) = o;
}

// ---------------- transpose + fp32->bf16 convert ----------------
__global__ void transpose_cvt(const float* __restrict__ in, u16* __restrict__ out,
                              int R, int C)
{
  __shared__ float t[32][33];
  const int bc = blockIdx.x * 32, br = blockIdx.y * 32;
  const int x = threadIdx.x;
#pragma unroll
  for (int i = threadIdx.y; i < 32; i += 8)
    t[i][x] = in[(size_t)(br + i) * C + bc + x];
  __syncthreads();
#pragma unroll
  for (int i = threadIdx.y; i < 32; i += 8)
    out[(size_t)(bc + i) * R + br + x] = f2bf(t[x][i]);
}

// ---------------- GEMM (2-phase dbuf, r12-verified): C = A * Bt^T + bias ----------------
__device__ __forceinline__ void store_out(float* p, float v) { *p = v; }
__device__ __forceinline__ void store_out(u16* p, float v)   { *p = f2bf(v); }

template <typename OutT>
__global__ __launch_bounds__(256) void gemm_bt(
    const u16* __restrict__ A, const u16* __restrict__ Bt,
    const float* __restrict__ bias, OutT* __restrict__ C,
    int M, int N, int K)
{
  __shared__ u16 As[2][128 * 32];
  __shared__ u16 Bs[2][128 * 32];
  const int tid = threadIdx.x;
  const int w = tid >> 6, l = tid & 63;
  const int g = l >> 4, li = l & 15;
  const int bm = blockIdx.y * 128, bn = blockIdx.x * 128;
  const int wr = (w >> 1) * 64, wc = (w & 1) * 64;

  f32x4 acc[4][4] = {};

  const int ar0 = tid >> 2,          as0 = tid & 3;
  const int ar1 = (tid + 256) >> 2,  as1 = (tid + 256) & 3;
  const u16* pa0 = A  + (size_t)(bm + ar0) * K + 8 * (as0 ^ (ar0 & 3));
  const u16* pa1 = A  + (size_t)(bm + ar1) * K + 8 * (as1 ^ (ar1 & 3));
  const u16* pb0 = Bt + (size_t)(bn + ar0) * K + 8 * (as0 ^ (ar0 & 3));
  const u16* pb1 = Bt + (size_t)(bn + ar1) * K + 8 * (as1 ^ (ar1 & 3));

  auto stage = [&](int b, int kt) {
    gload16(pa0 + kt, &As[b][w * 512]);
    gload16(pa1 + kt, &As[b][2048 + w * 512]);
    gload16(pb0 + kt, &Bs[b][w * 512]);
    gload16(pb1 + kt, &Bs[b][2048 + w * 512]);
  };

  stage(0, 0);

  int buf = 0;
  for (int kt = 0; kt < K; kt += 32) {
    __syncthreads();
    if (kt + 32 < K) stage(buf ^ 1, kt + 32);

    const u16* as = &As[buf][0];
    const u16* bs = &Bs[buf][0];

    s16x8 af[4], bf[4];
#pragma unroll
    for (int m = 0; m < 4; ++m) {
      const int row = wr + m * 16 + li;
      af[m] = *(const s16x8*)(as + row * 32 + 8 * (g ^ (row & 3)));
    }
#pragma unroll
    for (int n = 0; n < 4; ++n) {
      const int row = wc + n * 16 + li;
      bf[n] = *(const s16x8*)(bs + row * 32 + 8 * (g ^ (row & 3)));
    }
    __builtin_amdgcn_s_setprio(1);
#pragma unroll
    for (int m = 0; m < 4; ++m)
#pragma unroll
      for (int n = 0; n < 4; ++n)
        acc[m][n] = __builtin_amdgcn_mfma_f32_16x16x32_bf16(af[m], bf[n], acc[m][n], 0, 0, 0);
    __builtin_amdgcn_s_setprio(0);

    buf ^= 1;
  }

#pragma unroll
  for (int n = 0; n < 4; ++n) {
    const int col = bn + wc + n * 16 + li;
    const float bv = bias[col];
#pragma unroll
    for (int m = 0; m < 4; ++m) {
      const int row0 = bm + wr + m * 16 + g * 4;
#pragma unroll
      for (int r = 0; r < 4; ++r)
        store_out(C + (size_t)(row0 + r) * N + col, acc[m][n][r] + bv);
    }
  }
}

// ---------------- flash attention: swapped-operand S^T, lane-local softmax ----------------
// qkv: [4096][3072] bf16; out: [4096][1024] bf16
// grid 1024 (32 qt x 16 h x 2 b); block = 4 waves; each wave owns 16 q-rows (q = li).
__global__ __launch_bounds__(256, 4) void attn_kernel(
    const u16* __restrict__ qkv, u16* __restrict__ outp)
{
  __shared__ u16 Ks[2][4096];   // [kv][d] dbuf, 16B chunks XOR-swizzled by (kv&7)  (verified)
  __shared__ u16 Vt[4096];      // [d][kv] single, byte XOR ((d^(d>>3))&7)<<4       (verified)
  __shared__ u16 Pl[4 * 1024];  // per-wave P[q=li][64kv], byte XOR ((li&7)<<4)

  const int tid = threadIdx.x;
  const int w = tid >> 6, l = tid & 63;
  const int g = l >> 4, li = l & 15;

  // T1: bijective XCD swizzle (1024 = 8 * 128)
  const int lb = (blockIdx.x & 7) * 128 + (blockIdx.x >> 3);
  const int qt = lb & 31;
  const int h  = (lb >> 5) & 15;
  const int bb = lb >> 9;
  const size_t baserow = (size_t)bb * 2048;

  // hoisted Q fragments (unchanged; serve as B-operand now, same registers)
  const int qbase = qt * 64 + w * 16;
  const u16* qp = qkv + (baserow + qbase + li) * 3072 + h * 64 + 8 * g;
  const s16x8 qf0 = *(const s16x8*)(qp);
  const s16x8 qf1 = *(const s16x8*)(qp + 32);

  // K staging (verified): chunk c -> kv c>>3, slot c&7, pre-swizzled source
  const int kr0 = tid >> 3,         kc0 = tid & 7;
  const int kr1 = (tid + 256) >> 3, kc1 = (tid + 256) & 7;
  const u16* kg0 = qkv + (baserow + kr0) * 3072 + 1024 + h * 64 + 8 * (kc0 ^ (kr0 & 7));
  const u16* kg1 = qkv + (baserow + kr1) * 3072 + 1024 + h * 64 + 8 * (kc1 ^ (kr1 & 7));

  // V reg-staging: thread owns kv-pair vp x d-group dg
  const int vp = tid >> 3, dg = tid & 7;
  const u16* vgA = qkv + (baserow + 2 * vp)     * 3072 + 2048 + h * 64 + 8 * dg;
  const u16* vgB = qkv + (baserow + 2 * vp + 1) * 3072 + 2048 + h * 64 + 8 * dg;

  auto issueK = [&](int b, int t) {
    const size_t koff = (size_t)t * (64 * 3072);
    gload16(kg0 + koff, &Ks[b][w * 512]);
    gload16(kg1 + koff, &Ks[b][2048 + w * 512]);
  };

  // log2-domain online softmax; each lane owns q = li entirely (scalar state)
  const float C1  = 0.18033688f;   // 0.125 * log2(e)
  const float THR = 11.5416f;      // 8 * log2(e)
  float M = -1e30f;
  f32x4 o[4] = {}, os = {};        // o[nd][r] = O[q=li][d=nd*16+4g+r]; os[0] = rowsum

  s16x8 ones;
#pragma unroll
  for (int j = 0; j < 8; ++j) ones[j] = (short)0x3F80;   // bf16 1.0

  char* Pw = (char*)(Pl + w * 1024);
  const int pswz = (li & 7) << 4;

  // prologue: prefetch tile 0
  issueK(0, 0);
  s16x8 va = *(const s16x8*)vgA;
  s16x8 vb = *(const s16x8*)vgB;

  int buf = 0;
  for (int t = 0; t < 32; ++t) {
    // V regs (tile t) -> Vt; paired-kv b32 writes, verified swizzle involution
#pragma unroll
    for (int j = 0; j < 8; ++j) {
      const int d = 8 * dg + j;
      const u32 val = (u32)(u16)va[j] | ((u32)(u16)vb[j] << 16);
      *(u32*)((char*)Vt + d * 128 + ((4 * vp) ^ ((((d ^ (d >> 3)) & 7)) << 4))) = val;
    }
    __syncthreads();   // K[buf] gload drained; Vt visible

    if (t < 31) {      // prefetch next tile
      issueK(buf ^ 1, t + 1);
      const size_t koff = (size_t)(t + 1) * (64 * 3072);
      va = *(const s16x8*)(vgA + koff);
      vb = *(const s16x8*)(vgB + koff);
    }

    const u16* kb = &Ks[buf][0];

    // ---- S^T = K . Q^T (swapped operands; same regs, transposed output) ----
    // s[nk][r] = S^T[kv = nk*16 + 4g + r][q = li]
    f32x4 s[4] = {};
    __builtin_amdgcn_s_setprio(1);
#pragma unroll
    for (int nk = 0; nk < 4; ++nk) {
      const int kvr = nk * 16 + li;
      const s16x8 kf0 = *(const s16x8*)((const char*)kb + kvr * 128 + 16 * ((0 + g) ^ (kvr & 7)));
      const s16x8 kf1 = *(const s16x8*)((const char*)kb + kvr * 128 + 16 * ((4 + g) ^ (kvr & 7)));
      s[nk] = __builtin_amdgcn_mfma_f32_16x16x32_bf16(kf0, qf0, s[nk], 0, 0, 0);
      s[nk] = __builtin_amdgcn_mfma_f32_16x16x32_bf16(kf1, qf1, s[nk], 0, 0, 0);
    }
    __builtin_amdgcn_s_setprio(0);

    // ---- softmax: lane-local max over 16 + 2 shuffles over the g-axis ----
    float lm = fmaxf(fmaxf(s[0][0], s[0][1]), fmaxf(s[0][2], s[0][3]));
#pragma unroll
    for (int nk = 1; nk < 4; ++nk)
      lm = fmaxf(lm, fmaxf(fmaxf(s[nk][0], s[nk][1]), fmaxf(s[nk][2], s[nk][3])));
    lm = fmaxf(lm, __shfl_xor(lm, 16));
    lm = fmaxf(lm, __shfl_xor(lm, 32));
    lm *= C1;

    if (__any(lm > M + THR)) {       // T13 defer-max (rare)
      const float mn = fmaxf(M, lm);
      const float a = exp2g(M - mn);
      M = mn;
      os[0] *= a;
#pragma unroll
      for (int nd = 0; nd < 4; ++nd)
#pragma unroll
        for (int r = 0; r < 4; ++r) o[nd][r] *= a;
    }

    // ---- exp2 in place (P^T values, bounded by 2^THR) ----
#pragma unroll
    for (int nk = 0; nk < 4; ++nk)
#pragma unroll
      for (int r = 0; r < 4; ++r)
        s[nk][r] = exp2g(fmaf(s[nk][r], C1, -M));

    // ---- P -> LDS: cvt_pk pairs (consecutive kv), 4x ds_write_b64 ----
    // layout: row q=li (128B), byte kv*2 ^ pswz
#pragma unroll
    for (int nk = 0; nk < 4; ++nk) {
      u32 lo, hi;
      asm("v_cvt_pk_bf16_f32 %0, %1, %2" : "=v"(lo) : "v"(s[nk][0]), "v"(s[nk][1]));
      asm("v_cvt_pk_bf16_f32 %0, %1, %2" : "=v"(hi) : "v"(s[nk][2]), "v"(s[nk][3]));
      *(u32x2*)(Pw + li * 128 + ((nk * 32 + 8 * g) ^ pswz)) = (u32x2){lo, hi};
    }
    asm volatile("s_waitcnt lgkmcnt(0)" ::: "memory");

    // ---- O^T += V^T . P^T  (vf as A, pf as B; vf bytes unchanged) ----
    __builtin_amdgcn_s_setprio(1);
#pragma unroll
    for (int ks = 0; ks < 2; ++ks) {
      const s16x8 pf = *(const s16x8*)(Pw + li * 128 + ((ks * 64 + 16 * g) ^ pswz));
#pragma unroll
      for (int nd = 0; nd < 4; ++nd) {
        const int d = nd * 16 + li;
        const s16x8 vf = *(const s16x8*)((char*)Vt + d * 128 + ((ks * 64 + 16 * g) ^ (((d ^ (d >> 3)) & 7) << 4)));
        o[nd] = __builtin_amdgcn_mfma_f32_16x16x32_bf16(vf, pf, o[nd], 0, 0, 0);
      }
      os = __builtin_amdgcn_mfma_f32_16x16x32_bf16(ones, pf, os, 0, 0, 0);
    }
    __builtin_amdgcn_s_setprio(0);

    __syncthreads();   // all waves done with Ks[buf], Vt; prefetch drained
    buf ^= 1;
  }

  // ---- epilogue: O[q=li][d] / rowsum; 4 consecutive d per nd -> ushort4 ----
  const float inv = 1.0f / os[0];
  const size_t row = baserow + qbase + li;
#pragma unroll
  for (int nd = 0; nd < 4; ++nd) {
    ushort4 st;
    st.x = f2bf(o[nd][0] * inv);
    st.y = f2bf(o[nd][1] * inv);
    st.z = f2bf(o[nd][2] * inv);
    st.w = f2bf(o[nd][3] * inv);
    *(ushort4*)(outp + row * 1024 + h * 64 + nd * 16 + 4 * g) = st;
  }
}

// ---------------- launcher ----------------
extern "C" void kernel_launch(void* const* d_in, const int* in_sizes, int n_in,
                              void* d_out, int out_size, void* d_ws, size_t ws_size,
                              hipStream_t stream)
{
  const float* x     = (const float*)d_in[0];
  const float* gamma = (const float*)d_in[1];
  const float* beta  = (const float*)d_in[2];
  const float* Wqkv  = (const float*)d_in[3];
  const float* bqkv  = (const float*)d_in[4];
  const float* Wout  = (const float*)d_in[5];
  const float* bout  = (const float*)d_in[6];
  float* out = (float*)d_out;

  char* ws = (char*)d_ws;
  u16* xn     = (u16*)(ws);                       // 8 MB  [4096][1024]
  u16* wqkv_t = (u16*)(ws + ((size_t)8  << 20));  // 6 MB  [3072][1024]
  u16* wout_t = (u16*)(ws + ((size_t)14 << 20));  // 2 MB  [1024][1024]
  u16* qkv    = (u16*)(ws + ((size_t)16 << 20));  // 24 MB [4096][3072]
  u16* attn   = (u16*)(ws + ((size_t)40 << 20));  // 8 MB  [4096][1024]

  ln_kernel<<<4096, 256, 0, stream>>>(x, gamma, beta, xn);
  transpose_cvt<<<dim3(96, 32), dim3(32, 8), 0, stream>>>(Wqkv, wqkv_t, 1024, 3072);
  transpose_cvt<<<dim3(32, 32), dim3(32, 8), 0, stream>>>(Wout, wout_t, 1024, 1024);
  gemm_bt<u16><<<dim3(24, 32), 256, 0, stream>>>(xn, wqkv_t, bqkv, qkv, 4096, 3072, 1024);
  attn_kernel<<<1024, 256, 0, stream>>>(qkv, attn);
  gemm_bt<float><<<dim3(8, 32), 256, 0, stream>>>(attn, wout_t, bout, out, 4096, 1024, 1024);
}